// Round 1
// baseline (2399.187 us; speedup 1.0000x reference)
//
#include <hip/hip_runtime.h>

#define NP 500000
#define NA 25000

__device__ __forceinline__ float tanh_fast(float x) {
    float e = __expf(2.0f * x);
    return 1.0f - 2.0f / (e + 1.0f);
}

__device__ __forceinline__ void atomic_add_f32(float* p, float v) {
    __hip_atomic_fetch_add(p, v, __ATOMIC_RELAXED, __HIP_MEMORY_SCOPE_AGENT);
}

// ---------------------------------------------------------------------------
// K1: per-pair  h = tanh([p1[ii],p1[jj]] @ W_pi + b_pi)   (64 pairs/block)
//     i1_pre = einsum(h.reshape(32,8), basis)
//     i1 = tanh(i1_pre @ W_ii);  write i1; atomic p1_agg[ii] += i1
// ---------------------------------------------------------------------------
extern "C" __global__ __launch_bounds__(256, 2)
void k1_pairs(const int* __restrict__ ind2,
              const float* __restrict__ p1,
              const float* __restrict__ basis,
              const float* __restrict__ W_pi,
              const float* __restrict__ b_pi,
              const float* __restrict__ W_ii,
              float* __restrict__ out_i1,
              float* __restrict__ p1_agg)
{
    __shared__ float sX[128 * 64];   // x^T : [k][pair]            32 KB
    __shared__ float sB[32 * 256];   // W_pi K-tile / reused later 32 KB

    const int t = threadIdx.x;
    const int pair0 = blockIdx.x * 64;

    // ---- stage gathered x^T into sX[k][p]
    {
        const int pp = t >> 2;
        const int q  = t & 3;
        const int pr = pair0 + pp;
        const int prc = pr < NP ? pr : NP - 1;
        const int ia = ind2[2 * prc + 0];
        const int ja = ind2[2 * prc + 1];
        const float4* ri = (const float4*)(p1 + (size_t)ia * 64);
        const float4* rj = (const float4*)(p1 + (size_t)ja * 64);
        #pragma unroll
        for (int f = 0; f < 4; ++f) {
            float4 vi = ri[q * 4 + f];
            float4 vj = rj[q * 4 + f];
            int k0 = q * 16 + f * 4;
            sX[(k0 + 0) * 64 + pp] = vi.x;
            sX[(k0 + 1) * 64 + pp] = vi.y;
            sX[(k0 + 2) * 64 + pp] = vi.z;
            sX[(k0 + 3) * 64 + pp] = vi.w;
            sX[(64 + k0 + 0) * 64 + pp] = vj.x;
            sX[(64 + k0 + 1) * 64 + pp] = vj.y;
            sX[(64 + k0 + 2) * 64 + pp] = vj.z;
            sX[(64 + k0 + 3) * 64 + pp] = vj.w;
        }
    }

    const int ct = t & 15;   // col group: cols {4*ct + 64*i + j}
    const int pt = t >> 4;   // pair group: pairs 4*pt .. 4*pt+3

    float acc[4][16];
    #pragma unroll
    for (int p = 0; p < 4; ++p)
        #pragma unroll
        for (int n = 0; n < 16; ++n) acc[p][n] = 0.0f;

    // ---- GEMM: h = x @ W_pi  (K=128 in 4 tiles of 32)
    for (int kt = 0; kt < 4; ++kt) {
        __syncthreads();
        {
            const float4* src = (const float4*)(W_pi + kt * 32 * 256);
            float4* dst = (float4*)sB;
            #pragma unroll
            for (int f = 0; f < 8; ++f) dst[f * 256 + t] = src[f * 256 + t];
        }
        __syncthreads();
        #pragma unroll 4
        for (int k = 0; k < 32; ++k) {
            float4 a = *(const float4*)&sX[(kt * 32 + k) * 64 + 4 * pt];
            float av[4] = {a.x, a.y, a.z, a.w};
            #pragma unroll
            for (int i = 0; i < 4; ++i) {
                float4 b = *(const float4*)&sB[k * 256 + 4 * ct + 64 * i];
                float bv[4] = {b.x, b.y, b.z, b.w};
                #pragma unroll
                for (int p = 0; p < 4; ++p)
                    #pragma unroll
                    for (int j = 0; j < 4; ++j)
                        acc[p][i * 4 + j] = fmaf(av[p], bv[j], acc[p][i * 4 + j]);
            }
        }
    }

    // ---- bias + tanh (in place)
    #pragma unroll
    for (int i = 0; i < 4; ++i) {
        float4 bv = *(const float4*)&b_pi[4 * ct + 64 * i];
        float bb[4] = {bv.x, bv.y, bv.z, bv.w};
        #pragma unroll
        for (int p = 0; p < 4; ++p)
            #pragma unroll
            for (int j = 0; j < 4; ++j)
                acc[p][i * 4 + j] = tanh_fast(acc[p][i * 4 + j] + bb[j]);
    }

    // ---- i1_pre[p][c] = sum_b h[p][c*8+b] * basis[p][b]
    // thread cols 4ct+64i+j have c = 8i + (ct>>1), b = (ct&1)?4+j:j
    float pre[4][4];
    {
        const int boff = (ct & 1) ? 4 : 0;
        #pragma unroll
        for (int p = 0; p < 4; ++p) {
            const int pr = pair0 + 4 * pt + p;
            const int prc = pr < NP ? pr : NP - 1;
            float4 bs = *(const float4*)&basis[(size_t)prc * 8 + boff];
            #pragma unroll
            for (int i = 0; i < 4; ++i) {
                pre[p][i] = acc[p][i*4+0]*bs.x + acc[p][i*4+1]*bs.y
                          + acc[p][i*4+2]*bs.z + acc[p][i*4+3]*bs.w;
            }
        }
        #pragma unroll
        for (int p = 0; p < 4; ++p)
            #pragma unroll
            for (int i = 0; i < 4; ++i)
                pre[p][i] += __shfl_xor(pre[p][i], 1);
    }

    __syncthreads();                 // all GEMM reads of sB done; reuse region
    float* s_pre = sB;               // [32 c][64 p]   8 KB
    float* sWii  = sB + 32 * 64;     // [32 k][128]   16 KB
    if (!(ct & 1)) {
        const int ce = ct >> 1;
        #pragma unroll
        for (int i = 0; i < 4; ++i)
            #pragma unroll
            for (int p = 0; p < 4; ++p)
                s_pre[(8 * i + ce) * 64 + 4 * pt + p] = pre[p][i];
    }
    {
        const float4* src = (const float4*)W_ii;
        float4* dst = (float4*)sWii;
        #pragma unroll
        for (int f = 0; f < 4; ++f) dst[f * 256 + t] = src[f * 256 + t];
    }
    __syncthreads();

    // ---- i1 = tanh(i1_pre @ W_ii)  (64x128, K=32); thread cols {4ct+64i}, i<2
    float acc2[4][8];
    #pragma unroll
    for (int p = 0; p < 4; ++p)
        #pragma unroll
        for (int n = 0; n < 8; ++n) acc2[p][n] = 0.0f;
    #pragma unroll 4
    for (int k = 0; k < 32; ++k) {
        float4 a = *(const float4*)&s_pre[k * 64 + 4 * pt];
        float av[4] = {a.x, a.y, a.z, a.w};
        #pragma unroll
        for (int i = 0; i < 2; ++i) {
            float4 b = *(const float4*)&sWii[k * 128 + 4 * ct + 64 * i];
            float bv[4] = {b.x, b.y, b.z, b.w};
            #pragma unroll
            for (int p = 0; p < 4; ++p)
                #pragma unroll
                for (int j = 0; j < 4; ++j)
                    acc2[p][i * 4 + j] = fmaf(av[p], bv[j], acc2[p][i * 4 + j]);
        }
    }

    // ---- store i1 + atomic p1_agg[ii]
    #pragma unroll
    for (int p = 0; p < 4; ++p) {
        const int pr = pair0 + 4 * pt + p;
        if (pr < NP) {
            const int ia = ind2[2 * pr];
            float* dst = out_i1 + (size_t)pr * 128;
            float* ag  = p1_agg + (size_t)ia * 128;
            #pragma unroll
            for (int i = 0; i < 2; ++i) {
                float4 v;
                v.x = tanh_fast(acc2[p][i*4+0]);
                v.y = tanh_fast(acc2[p][i*4+1]);
                v.z = tanh_fast(acc2[p][i*4+2]);
                v.w = tanh_fast(acc2[p][i*4+3]);
                const int col = 4 * ct + 64 * i;
                *(float4*)&dst[col] = v;
                atomic_add_f32(&ag[col + 0], v.x);
                atomic_add_f32(&ag[col + 1], v.y);
                atomic_add_f32(&ag[col + 2], v.z);
                atomic_add_f32(&ag[col + 3], v.w);
            }
        }
    }
}

// ---------------------------------------------------------------------------
// K2: ix = (p3[ii]@wi_pix + p3[jj]@wj_pix + d3) * i1_1 ; write ix;
//     atomic p3_agg[ii] += ix.   64 pairs/block, 4 threads/pair.
// ---------------------------------------------------------------------------
extern "C" __global__ __launch_bounds__(256, 2)
void k2_pairs(const int* __restrict__ ind2,
              const float* __restrict__ p3,
              const float* __restrict__ d3,
              const float* __restrict__ wi_pix,
              const float* __restrict__ wj_pix,
              const float* __restrict__ i1buf,
              float* __restrict__ out_ix,
              float* __restrict__ p3_agg)
{
    __shared__ float sP3[192 * 64];  // [x*64+c][pair]  48 KB (reused i then j)
    __shared__ float sW[64 * 64];    // weight          16 KB (reused i then j)

    const int t = threadIdx.x;
    const int pair0 = blockIdx.x * 64;
    const int pp = t >> 2;           // local pair
    const int th = t & 3;            // col group: cols {4*th + 16*i + j}

    const int pr = pair0 + pp;
    const int prc = pr < NP ? pr : NP - 1;
    const int ia = ind2[2 * prc + 0];
    const int ja = ind2[2 * prc + 1];

    float acc[3][16];
    #pragma unroll
    for (int x = 0; x < 3; ++x)
        #pragma unroll
        for (int n = 0; n < 16; ++n) acc[x][n] = 0.0f;

    for (int pass = 0; pass < 2; ++pass) {
        __syncthreads();
        {
            const float4* src = (const float4*)(pass ? wj_pix : wi_pix);
            float4* dst = (float4*)sW;
            #pragma unroll
            for (int f = 0; f < 4; ++f) dst[f * 256 + t] = src[f * 256 + t];
        }
        {
            const float4* row = (const float4*)(p3 + (size_t)(pass ? ja : ia) * 192);
            #pragma unroll
            for (int f = 0; f < 12; ++f) {
                float4 v = row[f * 4 + th];
                const int cl = (f * 4 + th) * 4;   // x*64 + c
                sP3[(cl + 0) * 64 + pp] = v.x;
                sP3[(cl + 1) * 64 + pp] = v.y;
                sP3[(cl + 2) * 64 + pp] = v.z;
                sP3[(cl + 3) * 64 + pp] = v.w;
            }
        }
        __syncthreads();
        #pragma unroll 2
        for (int c = 0; c < 64; ++c) {
            float a0 = sP3[(0 * 64 + c) * 64 + pp];
            float a1 = sP3[(1 * 64 + c) * 64 + pp];
            float a2 = sP3[(2 * 64 + c) * 64 + pp];
            #pragma unroll
            for (int i = 0; i < 4; ++i) {
                float4 b = *(const float4*)&sW[c * 64 + 4 * th + 16 * i];
                float bv[4] = {b.x, b.y, b.z, b.w};
                #pragma unroll
                for (int j = 0; j < 4; ++j) {
                    acc[0][i*4+j] = fmaf(a0, bv[j], acc[0][i*4+j]);
                    acc[1][i*4+j] = fmaf(a1, bv[j], acc[1][i*4+j]);
                    acc[2][i*4+j] = fmaf(a2, bv[j], acc[2][i*4+j]);
                }
            }
        }
    }

    if (pr < NP) {
        const float dd[3] = {d3[3 * (size_t)pr + 0], d3[3 * (size_t)pr + 1], d3[3 * (size_t)pr + 2]};
        float* agg = p3_agg + (size_t)ia * 192;
        #pragma unroll
        for (int i = 0; i < 4; ++i) {
            const int col = 4 * th + 16 * i;
            float4 s = *(const float4*)&i1buf[(size_t)pr * 128 + 64 + col];
            float sv[4] = {s.x, s.y, s.z, s.w};
            #pragma unroll
            for (int x = 0; x < 3; ++x) {
                float4 v;
                v.x = (acc[x][i*4+0] + dd[x]) * sv[0];
                v.y = (acc[x][i*4+1] + dd[x]) * sv[1];
                v.z = (acc[x][i*4+2] + dd[x]) * sv[2];
                v.w = (acc[x][i*4+3] + dd[x]) * sv[3];
                *(float4*)&out_ix[((size_t)pr * 3 + x) * 64 + col] = v;
                atomic_add_f32(&agg[x * 64 + col + 0], v.x);
                atomic_add_f32(&agg[x * 64 + col + 1], v.y);
                atomic_add_f32(&agg[x * 64 + col + 2], v.z);
                atomic_add_f32(&agg[x * 64 + col + 3], v.w);
            }
        }
    }
}

// ---------------------------------------------------------------------------
// K3: per-atom tail. Wave per atom (lane = output column), 4 atoms/block.
// ---------------------------------------------------------------------------
extern "C" __global__ __launch_bounds__(256, 4)
void k3_atoms(const float* __restrict__ p1_agg,
              const float* __restrict__ p3_agg,
              const float* __restrict__ W_pp,
              const float* __restrict__ W_ppx,
              const float* __restrict__ wi_dot,
              const float* __restrict__ wj_dot,
              const float* __restrict__ W_pp1,
              const float* __restrict__ b_pp1,
              float* __restrict__ out_p1,
              float* __restrict__ out_p3,
              float* __restrict__ out_dot)
{
    __shared__ float s1[4][128];
    __shared__ float s3[4][192];
    __shared__ float sPm[4][192];
    __shared__ float sCat[4][128];

    const int w = threadIdx.x >> 6;
    const int l = threadIdx.x & 63;
    const int n = blockIdx.x * 4 + w;    // grid = 6250 exactly -> n < 25000

    s1[w][l]       = p1_agg[(size_t)n * 128 + l];
    s1[w][64 + l]  = p1_agg[(size_t)n * 128 + 64 + l];
    #pragma unroll
    for (int x = 0; x < 3; ++x)
        s3[w][x * 64 + l] = p3_agg[(size_t)n * 192 + x * 64 + l];
    __syncthreads();

    // p1_new = tanh(p1_agg @ W_pp)
    float pn = 0.0f;
    #pragma unroll 4
    for (int k = 0; k < 128; ++k)
        pn = fmaf(s1[w][k], W_pp[k * 64 + l], pn);
    pn = tanh_fast(pn);

    // p3_mixed = p3_agg @ W_ppx
    float pm[3];
    #pragma unroll
    for (int x = 0; x < 3; ++x) {
        float s = 0.0f;
        #pragma unroll 4
        for (int c = 0; c < 64; ++c)
            s = fmaf(s3[w][x * 64 + c], W_ppx[c * 64 + l], s);
        pm[x] = s;
        sPm[w][x * 64 + l] = s;
    }
    __syncthreads();

    // dotted = sum_x (pm@wi_dot)*(pm@wj_dot)
    float dot = 0.0f;
    #pragma unroll
    for (int x = 0; x < 3; ++x) {
        float vi = 0.0f, vj = 0.0f;
        #pragma unroll 4
        for (int c = 0; c < 64; ++c) {
            float a = sPm[w][x * 64 + c];
            vi = fmaf(a, wi_dot[c * 64 + l], vi);
            vj = fmaf(a, wj_dot[c * 64 + l], vj);
        }
        dot = fmaf(vi, vj, dot);
    }

    sCat[w][l]      = pn;
    sCat[w][64 + l] = dot;
    __syncthreads();

    // p1t1 = tanh([p1_new, dotted] @ W_pp1 + b_pp1); lane does cols l and 64+l
    float u1 = b_pp1[l];
    float u2 = b_pp1[64 + l];
    #pragma unroll 4
    for (int k = 0; k < 128; ++k) {
        float ck = sCat[w][k];
        u1 = fmaf(ck, W_pp1[k * 128 + l], u1);
        u2 = fmaf(ck, W_pp1[k * 128 + 64 + l], u2);
    }
    float p1o = tanh_fast(u1);
    float s3v = tanh_fast(u2);

    out_p1[(size_t)n * 64 + l]  = p1o;
    out_dot[(size_t)n * 64 + l] = dot;
    #pragma unroll
    for (int x = 0; x < 3; ++x)
        out_p3[((size_t)n * 3 + x) * 64 + l] = pm[x] * s3v;
}

// ---------------------------------------------------------------------------
extern "C" void kernel_launch(void* const* d_in, const int* in_sizes, int n_in,
                              void* d_out, int out_size, void* d_ws, size_t ws_size,
                              hipStream_t stream)
{
    const int*   ind2   = (const int*)d_in[0];
    const float* p1     = (const float*)d_in[1];
    const float* p3     = (const float*)d_in[2];
    const float* d3     = (const float*)d_in[3];
    const float* basis  = (const float*)d_in[4];
    const float* W_pi   = (const float*)d_in[5];
    const float* b_pi   = (const float*)d_in[6];
    const float* W_ii   = (const float*)d_in[7];
    const float* W_pp   = (const float*)d_in[8];
    const float* wi_pix = (const float*)d_in[9];
    const float* wj_pix = (const float*)d_in[10];
    const float* W_ppx  = (const float*)d_in[11];
    const float* wi_dot = (const float*)d_in[12];
    const float* wj_dot = (const float*)d_in[13];
    const float* W_pp1  = (const float*)d_in[14];
    const float* b_pp1  = (const float*)d_in[15];

    float* out     = (float*)d_out;
    float* out_p1  = out;                      // 25000*64   = 1,600,000
    float* out_p3  = out + 1600000;            // 25000*192  = 4,800,000
    float* out_dot = out + 6400000;            // 25000*64   = 1,600,000
    float* out_i1  = out + 8000000;            // 500000*128 = 64,000,000
    float* out_ix  = out + 72000000;           // 500000*192 = 96,000,000

    float* p1_agg = (float*)d_ws;              // 25000*128
    float* p3_agg = p1_agg + 25000 * 128;      // 25000*192

    hipMemsetAsync(d_ws, 0, (size_t)(25000 * 128 + 25000 * 192) * sizeof(float), stream);

    dim3 blk(256);
    k1_pairs<<<dim3(7813), blk, 0, stream>>>(ind2, p1, basis, W_pi, b_pi, W_ii,
                                             out_i1, p1_agg);
    k2_pairs<<<dim3(7813), blk, 0, stream>>>(ind2, p3, d3, wi_pix, wj_pix,
                                             out_i1, out_ix, p3_agg);
    k3_atoms<<<dim3(6250), blk, 0, stream>>>(p1_agg, p3_agg, W_pp, W_ppx,
                                             wi_dot, wj_dot, W_pp1, b_pp1,
                                             out_p1, out_p3, out_dot);
}

// Round 4
// 914.957 us; speedup vs baseline: 2.6222x; 2.6222x over previous
//
#include <hip/hip_runtime.h>

#define NP 500000
#define NA 25000

__device__ __forceinline__ float tanh_fast(float x) {
    float e = __expf(2.0f * x);
    return 1.0f - 2.0f / (e + 1.0f);
}

// readlane with proper float bitcast (__builtin_amdgcn_readlane is (int,int)!
// passing float would VALUE-convert = truncate — the R2/R3 bug).
__device__ __forceinline__ float readlane_f(float v, int lane) {
    int iv = __builtin_bit_cast(int, v);
    int r = __builtin_amdgcn_readlane(iv, lane);
    return __builtin_bit_cast(float, r);
}

__device__ __forceinline__ unsigned short f2bf(float x) {
    union { float f; unsigned int u; } c; c.f = x;
    unsigned int r = c.u + 0x7FFFu + ((c.u >> 16) & 1u);
    return (unsigned short)(r >> 16);
}
__device__ __forceinline__ float bf2f(unsigned short h) {
    union { unsigned int u; float f; } c; c.u = ((unsigned int)h) << 16;
    return c.f;
}

// ---------------------------------------------------------------------------
// K0a: per-atom  u = p1 @ W_pi[0:64,:] + b_pi ,  v = p1 @ W_pi[64:128,:]
// ---------------------------------------------------------------------------
extern "C" __global__ __launch_bounds__(256, 2)
void k0_uv(const float* __restrict__ p1,
           const float* __restrict__ W_pi,
           const float* __restrict__ b_pi,
           float* __restrict__ u,
           float* __restrict__ v)
{
    __shared__ float sW[32 * 256];
    __shared__ float sp1[4 * 64];

    const int t = threadIdx.x;
    const int a = t >> 6;
    const int c = t & 63;
    const int atom0 = blockIdx.x * 4;

    sp1[t] = p1[(size_t)(atom0 + a) * 64 + c];

    float accu[4] = {0, 0, 0, 0};
    float accv[4] = {0, 0, 0, 0};

    #pragma unroll
    for (int s = 0; s < 4; ++s) {
        __syncthreads();
        {
            const float4* src = (const float4*)(W_pi + s * 32 * 256);
            float4* dst = (float4*)sW;
            #pragma unroll
            for (int f = 0; f < 8; ++f) dst[f * 256 + t] = src[f * 256 + t];
        }
        __syncthreads();
        const int kbase = (s & 1) * 32;
        #pragma unroll 4
        for (int k = 0; k < 32; ++k) {
            float av = sp1[a * 64 + kbase + k];
            #pragma unroll
            for (int q = 0; q < 4; ++q) {
                float b = sW[k * 256 + c + 64 * q];
                if (s < 2) accu[q] = fmaf(av, b, accu[q]);
                else       accv[q] = fmaf(av, b, accv[q]);
            }
        }
    }

    #pragma unroll
    for (int q = 0; q < 4; ++q) {
        const int col = c + 64 * q;
        u[(size_t)(atom0 + a) * 256 + col] = accu[q] + b_pi[col];
        v[(size_t)(atom0 + a) * 256 + col] = accv[q];
    }
}

// ---------------------------------------------------------------------------
// K0b: qi = p3 @ wi_pix , qj = p3 @ wj_pix   (bf16 outputs, rows = 75000)
// ---------------------------------------------------------------------------
extern "C" __global__ __launch_bounds__(256, 4)
void k0_q(const float* __restrict__ p3,
          const float* __restrict__ wi_pix,
          const float* __restrict__ wj_pix,
          unsigned short* __restrict__ qi_bf,
          unsigned short* __restrict__ qj_bf)
{
    __shared__ float sWi[64 * 64];
    __shared__ float sWj[64 * 64];

    const int t = threadIdx.x;
    {
        const float4* si = (const float4*)wi_pix;
        const float4* sj = (const float4*)wj_pix;
        float4* di = (float4*)sWi;
        float4* dj = (float4*)sWj;
        #pragma unroll
        for (int f = 0; f < 4; ++f) { di[f * 256 + t] = si[f * 256 + t]; dj[f * 256 + t] = sj[f * 256 + t]; }
    }
    __syncthreads();

    const int w = t >> 6;
    const int l = t & 63;
    const size_t r = (size_t)blockIdx.x * 4 + w;    // < 75000

    float val = p3[r * 64 + l];
    float ai = 0.0f, aj = 0.0f;
    #pragma unroll
    for (int k = 0; k < 64; ++k) {
        float a = readlane_f(val, k);
        ai = fmaf(a, sWi[k * 64 + l], ai);
        aj = fmaf(a, sWj[k * 64 + l], aj);
    }
    qi_bf[r * 64 + l] = f2bf(ai);
    qj_bf[r * 64 + l] = f2bf(aj);
}

// ---------------------------------------------------------------------------
// CSR build
// ---------------------------------------------------------------------------
extern "C" __global__ void k_count(const int* __restrict__ ind2, int* __restrict__ cnt)
{
    int p = blockIdx.x * 256 + threadIdx.x;
    if (p < NP) atomicAdd(&cnt[ind2[2 * p]], 1);
}

extern "C" __global__ __launch_bounds__(1024)
void csr_scan(const int* __restrict__ cnt, int* __restrict__ rowstart)
{
    __shared__ int ssum[1024];
    const int t = threadIdx.x;
    const int base = t * 25;

    int s = 0;
    #pragma unroll 5
    for (int i = 0; i < 25; ++i) {
        int idx = base + i;
        s += (idx < NA) ? cnt[idx] : 0;
    }
    ssum[t] = s;
    __syncthreads();
    for (int off = 1; off < 1024; off <<= 1) {
        int vv = (t >= off) ? ssum[t - off] : 0;
        __syncthreads();
        ssum[t] += vv;
        __syncthreads();
    }
    int run = (t > 0) ? ssum[t - 1] : 0;
    for (int i = 0; i < 25; ++i) {
        int idx = base + i;
        if (idx <= NA) rowstart[idx] = run;
        run += (idx < NA) ? cnt[idx] : 0;
    }
}

extern "C" __global__ void k_scatter(const int* __restrict__ ind2,
                                     const int* __restrict__ rowstart,
                                     int* __restrict__ cursor,
                                     int* __restrict__ plist)
{
    int p = blockIdx.x * 256 + threadIdx.x;
    if (p < NP) {
        int ii = ind2[2 * p];
        int pos = atomicAdd(&cursor[ii], 1);
        plist[rowstart[ii] + pos] = p;
    }
}

// ---------------------------------------------------------------------------
// K_pair_i1: wave per atom. h = tanh(u[ii]+v[jj]); pre = einsum(h,basis);
//            i1 = tanh(pre @ W_ii). Write i1; reg-accumulate p1_agg.
// ---------------------------------------------------------------------------
extern "C" __global__ __launch_bounds__(256, 4)
void k_pair_i1(const int* __restrict__ ind2,
               const float* __restrict__ basis,
               const float* __restrict__ W_ii,
               const float* __restrict__ u,
               const float* __restrict__ v,
               const int* __restrict__ rowstart,
               const int* __restrict__ plist,
               float* __restrict__ out_i1,
               float* __restrict__ aggA,
               float* __restrict__ aggB)
{
    const int t = threadIdx.x;
    const int w = t >> 6;
    const int l = t & 63;
    const int n = blockIdx.x * 4 + w;        // grid 6250*4 = 25000 exactly

    float wA[32], wB[32];
    #pragma unroll
    for (int c = 0; c < 32; ++c) {
        wA[c] = W_ii[c * 128 + l];
        wB[c] = W_ii[c * 128 + 64 + l];
    }

    float uu[4];
    #pragma unroll
    for (int q = 0; q < 4; ++q) uu[q] = u[(size_t)n * 256 + 64 * q + l];

    const int start = rowstart[n];
    const int end   = rowstart[n + 1];

    float agg1a = 0.0f, agg1b = 0.0f;

    for (int it = start; it < end; ++it) {
        const int p  = plist[it];
        const int jj = ind2[2 * p + 1];

        float hq[4];
        #pragma unroll
        for (int q = 0; q < 4; ++q)
            hq[q] = tanh_fast(uu[q] + v[(size_t)jj * 256 + 64 * q + l]);

        const float bs = basis[(size_t)p * 8 + (l & 7)];
        float pre[4];
        #pragma unroll
        for (int q = 0; q < 4; ++q) {
            float s = hq[q] * bs;
            s += __shfl_xor(s, 1);
            s += __shfl_xor(s, 2);
            s += __shfl_xor(s, 4);
            pre[q] = s;
        }

        float a0 = 0.0f, a1 = 0.0f;
        #pragma unroll
        for (int c = 0; c < 32; ++c) {
            float pc = readlane_f(pre[c >> 3], 8 * (c & 7));
            a0 = fmaf(pc, wA[c], a0);
            a1 = fmaf(pc, wB[c], a1);
        }
        const float i10 = tanh_fast(a0);
        const float i11 = tanh_fast(a1);

        out_i1[(size_t)p * 128 + l]      = i10;
        out_i1[(size_t)p * 128 + 64 + l] = i11;
        agg1a += i10;
        agg1b += i11;
    }

    aggA[(size_t)n * 64 + l] = agg1a;
    aggB[(size_t)n * 64 + l] = agg1b;
}

// ---------------------------------------------------------------------------
// K_pair_ix: wave per atom. ix = (qi[ii]+qj[jj]+d3)*i1_1 (i1_1 from out_i1).
//            Write ix; reg-accumulate p3_agg -> out_p3 region.
// ---------------------------------------------------------------------------
extern "C" __global__ __launch_bounds__(256, 4)
void k_pair_ix(const int* __restrict__ ind2,
               const float* __restrict__ d3,
               const unsigned short* __restrict__ qi_bf,
               const unsigned short* __restrict__ qj_bf,
               const float* __restrict__ i1buf,
               const int* __restrict__ rowstart,
               const int* __restrict__ plist,
               float* __restrict__ out_ix,
               float* __restrict__ p3r)
{
    const int t = threadIdx.x;
    const int w = t >> 6;
    const int l = t & 63;
    const int n = blockIdx.x * 4 + w;

    float qiv[3];
    #pragma unroll
    for (int x = 0; x < 3; ++x) qiv[x] = bf2f(qi_bf[(size_t)n * 192 + 64 * x + l]);

    const int start = rowstart[n];
    const int end   = rowstart[n + 1];

    float agg3[3] = {0.0f, 0.0f, 0.0f};

    for (int it = start; it < end; ++it) {
        const int p  = plist[it];
        const int jj = ind2[2 * p + 1];

        const float i11 = i1buf[(size_t)p * 128 + 64 + l];
        const float dd[3] = {d3[3 * (size_t)p + 0], d3[3 * (size_t)p + 1], d3[3 * (size_t)p + 2]};
        #pragma unroll
        for (int x = 0; x < 3; ++x) {
            float ixv = (qiv[x] + bf2f(qj_bf[(size_t)jj * 192 + 64 * x + l]) + dd[x]) * i11;
            out_ix[((size_t)p * 3 + x) * 64 + l] = ixv;
            agg3[x] += ixv;
        }
    }

    #pragma unroll
    for (int x = 0; x < 3; ++x)
        p3r[(size_t)n * 192 + 64 * x + l] = agg3[x];
}

// ---------------------------------------------------------------------------
// K3: per-atom tail. Reads aggs from out regions, overwrites with finals.
// ---------------------------------------------------------------------------
extern "C" __global__ __launch_bounds__(256, 4)
void k3_atoms(float* rP1, float* rDOT, float* rP3,
              const float* __restrict__ W_pp,
              const float* __restrict__ W_ppx,
              const float* __restrict__ wi_dot,
              const float* __restrict__ wj_dot,
              const float* __restrict__ W_pp1,
              const float* __restrict__ b_pp1)
{
    __shared__ float s1[4][128];
    __shared__ float s3[4][192];
    __shared__ float sPm[4][192];
    __shared__ float sCat[4][128];

    const int w = threadIdx.x >> 6;
    const int l = threadIdx.x & 63;
    const int n = blockIdx.x * 4 + w;    // grid = 6250 exactly

    s1[w][l]       = rP1[(size_t)n * 64 + l];
    s1[w][64 + l]  = rDOT[(size_t)n * 64 + l];
    #pragma unroll
    for (int x = 0; x < 3; ++x)
        s3[w][x * 64 + l] = rP3[(size_t)n * 192 + x * 64 + l];
    __syncthreads();

    // p1_new = tanh(p1_agg @ W_pp)
    float pn = 0.0f;
    #pragma unroll 4
    for (int k = 0; k < 128; ++k)
        pn = fmaf(s1[w][k], W_pp[k * 64 + l], pn);
    pn = tanh_fast(pn);

    // p3_mixed = p3_agg @ W_ppx
    float pm[3];
    #pragma unroll
    for (int x = 0; x < 3; ++x) {
        float s = 0.0f;
        #pragma unroll 4
        for (int c = 0; c < 64; ++c)
            s = fmaf(s3[w][x * 64 + c], W_ppx[c * 64 + l], s);
        pm[x] = s;
        sPm[w][x * 64 + l] = s;
    }
    __syncthreads();

    // dotted = sum_x (pm@wi_dot)*(pm@wj_dot)
    float dot = 0.0f;
    #pragma unroll
    for (int x = 0; x < 3; ++x) {
        float vi = 0.0f, vj = 0.0f;
        #pragma unroll 4
        for (int c = 0; c < 64; ++c) {
            float a = sPm[w][x * 64 + c];
            vi = fmaf(a, wi_dot[c * 64 + l], vi);
            vj = fmaf(a, wj_dot[c * 64 + l], vj);
        }
        dot = fmaf(vi, vj, dot);
    }

    sCat[w][l]      = pn;
    sCat[w][64 + l] = dot;
    __syncthreads();

    float u1 = b_pp1[l];
    float u2 = b_pp1[64 + l];
    #pragma unroll 4
    for (int k = 0; k < 128; ++k) {
        float ck = sCat[w][k];
        u1 = fmaf(ck, W_pp1[k * 128 + l], u1);
        u2 = fmaf(ck, W_pp1[k * 128 + 64 + l], u2);
    }
    float p1o = tanh_fast(u1);
    float s3v = tanh_fast(u2);

    rP1[(size_t)n * 64 + l]  = p1o;
    rDOT[(size_t)n * 64 + l] = dot;
    #pragma unroll
    for (int x = 0; x < 3; ++x)
        rP3[(size_t)n * 192 + x * 64 + l] = pm[x] * s3v;
}

// ---------------------------------------------------------------------------
extern "C" void kernel_launch(void* const* d_in, const int* in_sizes, int n_in,
                              void* d_out, int out_size, void* d_ws, size_t ws_size,
                              hipStream_t stream)
{
    const int*   ind2   = (const int*)d_in[0];
    const float* p1     = (const float*)d_in[1];
    const float* p3     = (const float*)d_in[2];
    const float* d3     = (const float*)d_in[3];
    const float* basis  = (const float*)d_in[4];
    const float* W_pi   = (const float*)d_in[5];
    const float* b_pi   = (const float*)d_in[6];
    const float* W_ii   = (const float*)d_in[7];
    const float* W_pp   = (const float*)d_in[8];
    const float* wi_pix = (const float*)d_in[9];
    const float* wj_pix = (const float*)d_in[10];
    const float* W_ppx  = (const float*)d_in[11];
    const float* wi_dot = (const float*)d_in[12];
    const float* wj_dot = (const float*)d_in[13];
    const float* W_pp1  = (const float*)d_in[14];
    const float* b_pp1  = (const float*)d_in[15];

    float* out     = (float*)d_out;
    float* out_p1  = out;                      // 25000*64 ; doubles as agg1a scratch
    float* out_p3  = out + 1600000;            // 25000*192; doubles as p3_agg scratch
    float* out_dot = out + 6400000;            // 25000*64 ; doubles as agg1b scratch
    float* out_i1  = out + 8000000;            // 500000*128
    float* out_ix  = out + 72000000;           // 500000*192

    // u,v scratch inside out_ix region (dead before out_ix is written)
    float* u = out_ix;                         // 6,400,000 floats
    float* v = out_ix + 6400000;               // 6,400,000 floats

    // d_ws: CSR ints + bf16 qi/qj  (total ~21.5 MB)
    int* cnt      = (int*)d_ws;                // 25,000
    int* rowstart = cnt + 25000;               // 25,001
    int* cursor   = rowstart + 25001;          // 25,000
    int* plist    = cursor + 25000;            // 500,000
    unsigned short* qi_bf = (unsigned short*)(plist + 500000);  // 4,800,000
    unsigned short* qj_bf = qi_bf + 4800000;                    // 4,800,000

    hipMemsetAsync(d_ws, 0, (size_t)75001 * sizeof(int), stream);

    dim3 blk(256);
    k0_uv    <<<dim3(6250),  blk, 0, stream>>>(p1, W_pi, b_pi, u, v);
    k0_q     <<<dim3(18750), blk, 0, stream>>>(p3, wi_pix, wj_pix, qi_bf, qj_bf);
    k_count  <<<dim3(1954),  blk, 0, stream>>>(ind2, cnt);
    csr_scan <<<dim3(1), dim3(1024), 0, stream>>>(cnt, rowstart);
    k_scatter<<<dim3(1954),  blk, 0, stream>>>(ind2, rowstart, cursor, plist);
    k_pair_i1<<<dim3(6250),  blk, 0, stream>>>(ind2, basis, W_ii, u, v,
                                               rowstart, plist, out_i1,
                                               out_p1, out_dot);
    k_pair_ix<<<dim3(6250),  blk, 0, stream>>>(ind2, d3, qi_bf, qj_bf, out_i1,
                                               rowstart, plist, out_ix, out_p3);
    k3_atoms <<<dim3(6250),  blk, 0, stream>>>(out_p1, out_dot, out_p3,
                                               W_pp, W_ppx, wi_dot, wj_dot,
                                               W_pp1, b_pp1);
}

// Round 5
// 722.307 us; speedup vs baseline: 3.3216x; 1.2667x over previous
//
#include <hip/hip_runtime.h>

#define NP 500000
#define NA 25000

__device__ __forceinline__ float tanh_fast(float x) {
    float e = __expf(2.0f * x);
    return 1.0f - 2.0f / (e + 1.0f);
}

// readlane with float bitcast (__builtin_amdgcn_readlane is (int,int);
// passing float value-converts = truncates — the R2/R3 bug).
__device__ __forceinline__ float readlane_f(float v, int lane) {
    int iv = __builtin_bit_cast(int, v);
    int r = __builtin_amdgcn_readlane(iv, lane);
    return __builtin_bit_cast(float, r);
}

__device__ __forceinline__ unsigned short f2bf(float x) {
    union { float f; unsigned int u; } c; c.f = x;
    unsigned int r = c.u + 0x7FFFu + ((c.u >> 16) & 1u);
    return (unsigned short)(r >> 16);
}
__device__ __forceinline__ float bf2f(unsigned short h) {
    union { unsigned int u; float f; } c; c.u = ((unsigned int)h) << 16;
    return c.f;
}

// ---------------------------------------------------------------------------
// K0a: per-atom  u = p1 @ W_pi[0:64,:] + b_pi (f32, [atom][col]),
//                v = p1 @ W_pi[64:128,:]      (bf16, [atom][l*4+q], col=64q+l)
// ---------------------------------------------------------------------------
extern "C" __global__ __launch_bounds__(256, 2)
void k0_uv(const float* __restrict__ p1,
           const float* __restrict__ W_pi,
           const float* __restrict__ b_pi,
           float* __restrict__ u,
           unsigned short* __restrict__ v_bf)
{
    __shared__ float sW[32 * 256];
    __shared__ float sp1[4 * 64];

    const int t = threadIdx.x;
    const int a = t >> 6;
    const int c = t & 63;
    const int atom0 = blockIdx.x * 4;

    sp1[t] = p1[(size_t)(atom0 + a) * 64 + c];

    float accu[4] = {0, 0, 0, 0};
    float accv[4] = {0, 0, 0, 0};

    #pragma unroll
    for (int s = 0; s < 4; ++s) {
        __syncthreads();
        {
            const float4* src = (const float4*)(W_pi + s * 32 * 256);
            float4* dst = (float4*)sW;
            #pragma unroll
            for (int f = 0; f < 8; ++f) dst[f * 256 + t] = src[f * 256 + t];
        }
        __syncthreads();
        const int kbase = (s & 1) * 32;
        #pragma unroll 4
        for (int k = 0; k < 32; ++k) {
            float av = sp1[a * 64 + kbase + k];
            #pragma unroll
            for (int q = 0; q < 4; ++q) {
                float b = sW[k * 256 + c + 64 * q];
                if (s < 2) accu[q] = fmaf(av, b, accu[q]);
                else       accv[q] = fmaf(av, b, accv[q]);
            }
        }
    }

    const int atom = atom0 + a;
    #pragma unroll
    for (int q = 0; q < 4; ++q)
        u[(size_t)atom * 256 + c + 64 * q] = accu[q] + b_pi[c + 64 * q];
    ushort4 vv;
    vv.x = f2bf(accv[0]); vv.y = f2bf(accv[1]);
    vv.z = f2bf(accv[2]); vv.w = f2bf(accv[3]);
    *(ushort4*)&v_bf[(size_t)atom * 256 + 4 * c] = vv;
}

// ---------------------------------------------------------------------------
// K0b: qi = p3 @ wi_pix, qj = p3 @ wj_pix  (bf16, [atom][l*4+x], slot 3 pad)
// wave per atom.
// ---------------------------------------------------------------------------
extern "C" __global__ __launch_bounds__(256, 4)
void k0_q(const float* __restrict__ p3,
          const float* __restrict__ wi_pix,
          const float* __restrict__ wj_pix,
          unsigned short* __restrict__ qi_bf,
          unsigned short* __restrict__ qj_bf)
{
    __shared__ float sWi[64 * 64];
    __shared__ float sWj[64 * 64];

    const int t = threadIdx.x;
    {
        const float4* si = (const float4*)wi_pix;
        const float4* sj = (const float4*)wj_pix;
        float4* di = (float4*)sWi;
        float4* dj = (float4*)sWj;
        #pragma unroll
        for (int f = 0; f < 4; ++f) { di[f * 256 + t] = si[f * 256 + t]; dj[f * 256 + t] = sj[f * 256 + t]; }
    }
    __syncthreads();

    const int w = t >> 6;
    const int l = t & 63;
    const int atom = blockIdx.x * 4 + w;     // grid 6250 -> < 25000

    float val0 = p3[((size_t)atom * 3 + 0) * 64 + l];
    float val1 = p3[((size_t)atom * 3 + 1) * 64 + l];
    float val2 = p3[((size_t)atom * 3 + 2) * 64 + l];

    float ai[3] = {0, 0, 0}, aj[3] = {0, 0, 0};
    #pragma unroll 8
    for (int k = 0; k < 64; ++k) {
        float a0 = readlane_f(val0, k);
        float a1 = readlane_f(val1, k);
        float a2 = readlane_f(val2, k);
        float wi = sWi[k * 64 + l];
        float wj = sWj[k * 64 + l];
        ai[0] = fmaf(a0, wi, ai[0]); aj[0] = fmaf(a0, wj, aj[0]);
        ai[1] = fmaf(a1, wi, ai[1]); aj[1] = fmaf(a1, wj, aj[1]);
        ai[2] = fmaf(a2, wi, ai[2]); aj[2] = fmaf(a2, wj, aj[2]);
    }
    ushort4 pi, pj;
    pi.x = f2bf(ai[0]); pi.y = f2bf(ai[1]); pi.z = f2bf(ai[2]); pi.w = 0;
    pj.x = f2bf(aj[0]); pj.y = f2bf(aj[1]); pj.z = f2bf(aj[2]); pj.w = 0;
    *(ushort4*)&qi_bf[(size_t)atom * 256 + 4 * l] = pi;
    *(ushort4*)&qj_bf[(size_t)atom * 256 + 4 * l] = pj;
}

// ---------------------------------------------------------------------------
// CSR build
// ---------------------------------------------------------------------------
extern "C" __global__ void k_count(const int* __restrict__ ind2, int* __restrict__ cnt)
{
    int p = blockIdx.x * 256 + threadIdx.x;
    if (p < NP) atomicAdd(&cnt[ind2[2 * p]], 1);
}

extern "C" __global__ __launch_bounds__(1024)
void csr_scan(const int* __restrict__ cnt, int* __restrict__ rowstart)
{
    __shared__ int ssum[1024];
    const int t = threadIdx.x;
    const int base = t * 25;

    int s = 0;
    #pragma unroll 5
    for (int i = 0; i < 25; ++i) {
        int idx = base + i;
        s += (idx < NA) ? cnt[idx] : 0;
    }
    ssum[t] = s;
    __syncthreads();
    for (int off = 1; off < 1024; off <<= 1) {
        int vv = (t >= off) ? ssum[t - off] : 0;
        __syncthreads();
        ssum[t] += vv;
        __syncthreads();
    }
    int run = (t > 0) ? ssum[t - 1] : 0;
    for (int i = 0; i < 25; ++i) {
        int idx = base + i;
        if (idx <= NA) rowstart[idx] = run;
        run += (idx < NA) ? cnt[idx] : 0;
    }
}

extern "C" __global__ void k_scatter(const int* __restrict__ ind2,
                                     const int* __restrict__ rowstart,
                                     int* __restrict__ cursor,
                                     int* __restrict__ plist)
{
    int p = blockIdx.x * 256 + threadIdx.x;
    if (p < NP) {
        int ii = ind2[2 * p];
        int pos = atomicAdd(&cursor[ii], 1);
        plist[rowstart[ii] + pos] = p;
    }
}

// ---------------------------------------------------------------------------
// K_pair (merged): wave per atom; per pair:
//   h = tanh(u[ii]+v[jj]); pre = einsum(h,basis); i1 = tanh(pre @ W_ii)
//   ix = (qi[ii]+qj[jj]+d3)*i1_1   (i11 stays in registers!)
// 2-deep pipelined uniform/gather loads. Reg-accumulated aggs.
// ---------------------------------------------------------------------------
extern "C" __global__ __launch_bounds__(256, 3)
void k_pair(const int* __restrict__ ind2,
            const float* __restrict__ d3,
            const float* __restrict__ basis,
            const float* __restrict__ W_ii,
            const float* __restrict__ u,
            const unsigned short* __restrict__ v_bf,
            const unsigned short* __restrict__ qi_bf,
            const unsigned short* __restrict__ qj_bf,
            const int* __restrict__ rowstart,
            const int* __restrict__ plist,
            float* __restrict__ out_i1,
            float* __restrict__ out_ix,
            float* __restrict__ p1_agg,
            float* __restrict__ p3_agg)
{
    const int t = threadIdx.x;
    const int w = t >> 6;
    const int l = t & 63;
    const int n = blockIdx.x * 4 + w;        // grid 6250*4 = 25000 exactly

    float wA[32], wB[32];
    #pragma unroll
    for (int c = 0; c < 32; ++c) {
        wA[c] = W_ii[c * 128 + l];
        wB[c] = W_ii[c * 128 + 64 + l];
    }

    float uu[4];
    #pragma unroll
    for (int q = 0; q < 4; ++q) uu[q] = u[(size_t)n * 256 + 64 * q + l];
    float qiv[3];
    {
        ushort4 qv = *(const ushort4*)&qi_bf[(size_t)n * 256 + 4 * l];
        qiv[0] = bf2f(qv.x); qiv[1] = bf2f(qv.y); qiv[2] = bf2f(qv.z);
    }

    const int start = rowstart[n];
    const int end   = rowstart[n + 1];

    float agg1a = 0.0f, agg1b = 0.0f;
    float agg3[3] = {0.0f, 0.0f, 0.0f};

    if (start < end) {
        // stage A = pair data for iteration `it`; stage B prefetched
        int pA = plist[start];
        int jjA = ind2[2 * pA + 1];
        ushort4 vA = *(const ushort4*)&v_bf[(size_t)jjA * 256 + 4 * l];
        ushort4 qA = *(const ushort4*)&qj_bf[(size_t)jjA * 256 + 4 * l];
        float bsA = basis[(size_t)pA * 8 + (l & 7)];
        float dA0 = d3[3 * (size_t)pA + 0];
        float dA1 = d3[3 * (size_t)pA + 1];
        float dA2 = d3[3 * (size_t)pA + 2];
        int idx1 = (start + 1 < end) ? start + 1 : start;
        int pB = plist[idx1];
        int jjB = ind2[2 * pB + 1];

        for (int it = start; it < end; ++it) {
            // issue next-pair loads (stage B data)
            ushort4 vB = *(const ushort4*)&v_bf[(size_t)jjB * 256 + 4 * l];
            ushort4 qB = *(const ushort4*)&qj_bf[(size_t)jjB * 256 + 4 * l];
            float bsB = basis[(size_t)pB * 8 + (l & 7)];
            float dB0 = d3[3 * (size_t)pB + 0];
            float dB1 = d3[3 * (size_t)pB + 1];
            float dB2 = d3[3 * (size_t)pB + 2];
            int idx2 = (it + 2 < end) ? it + 2 : it;
            int pC = plist[idx2];
            int jjC = ind2[2 * pC + 1];

            // ---- compute with stage A ----
            float hq[4];
            hq[0] = tanh_fast(uu[0] + bf2f(vA.x));
            hq[1] = tanh_fast(uu[1] + bf2f(vA.y));
            hq[2] = tanh_fast(uu[2] + bf2f(vA.z));
            hq[3] = tanh_fast(uu[3] + bf2f(vA.w));

            float pre[4];
            #pragma unroll
            for (int q = 0; q < 4; ++q) {
                float s = hq[q] * bsA;
                s += __shfl_xor(s, 1);
                s += __shfl_xor(s, 2);
                s += __shfl_xor(s, 4);
                pre[q] = s;
            }

            float a00 = 0, a01 = 0, a10 = 0, a11 = 0;
            #pragma unroll
            for (int c = 0; c < 32; c += 2) {
                float p0 = readlane_f(pre[c >> 3], 8 * (c & 7));
                float p1 = readlane_f(pre[(c + 1) >> 3], 8 * ((c + 1) & 7));
                a00 = fmaf(p0, wA[c], a00);     a10 = fmaf(p0, wB[c], a10);
                a01 = fmaf(p1, wA[c + 1], a01); a11 = fmaf(p1, wB[c + 1], a11);
            }
            const float i10 = tanh_fast(a00 + a01);
            const float i11 = tanh_fast(a10 + a11);

            out_i1[(size_t)pA * 128 + l]      = i10;
            out_i1[(size_t)pA * 128 + 64 + l] = i11;
            agg1a += i10;
            agg1b += i11;

            float ix0 = (qiv[0] + bf2f(qA.x) + dA0) * i11;
            float ix1 = (qiv[1] + bf2f(qA.y) + dA1) * i11;
            float ix2 = (qiv[2] + bf2f(qA.z) + dA2) * i11;
            out_ix[((size_t)pA * 3 + 0) * 64 + l] = ix0;
            out_ix[((size_t)pA * 3 + 1) * 64 + l] = ix1;
            out_ix[((size_t)pA * 3 + 2) * 64 + l] = ix2;
            agg3[0] += ix0; agg3[1] += ix1; agg3[2] += ix2;

            // rotate stages
            pA = pB; vA = vB; qA = qB; bsA = bsB;
            dA0 = dB0; dA1 = dB1; dA2 = dB2;
            pB = pC; jjB = jjC;
        }
    }

    p1_agg[(size_t)n * 128 + l]      = agg1a;
    p1_agg[(size_t)n * 128 + 64 + l] = agg1b;
    #pragma unroll
    for (int x = 0; x < 3; ++x)
        p3_agg[(size_t)n * 192 + 64 * x + l] = agg3[x];
}

// ---------------------------------------------------------------------------
// K3: per-atom tail.
// ---------------------------------------------------------------------------
extern "C" __global__ __launch_bounds__(256, 4)
void k3_atoms(const float* __restrict__ p1_agg,
              const float* __restrict__ p3_agg,
              const float* __restrict__ W_pp,
              const float* __restrict__ W_ppx,
              const float* __restrict__ wi_dot,
              const float* __restrict__ wj_dot,
              const float* __restrict__ W_pp1,
              const float* __restrict__ b_pp1,
              float* __restrict__ out_p1,
              float* __restrict__ out_p3,
              float* __restrict__ out_dot)
{
    __shared__ float s1[4][128];
    __shared__ float s3[4][192];
    __shared__ float sPm[4][192];
    __shared__ float sCat[4][128];

    const int w = threadIdx.x >> 6;
    const int l = threadIdx.x & 63;
    const int n = blockIdx.x * 4 + w;    // grid = 6250 exactly

    s1[w][l]      = p1_agg[(size_t)n * 128 + l];
    s1[w][64 + l] = p1_agg[(size_t)n * 128 + 64 + l];
    #pragma unroll
    for (int x = 0; x < 3; ++x)
        s3[w][x * 64 + l] = p3_agg[(size_t)n * 192 + x * 64 + l];
    __syncthreads();

    float pn = 0.0f;
    #pragma unroll 4
    for (int k = 0; k < 128; ++k)
        pn = fmaf(s1[w][k], W_pp[k * 64 + l], pn);
    pn = tanh_fast(pn);

    float pm[3];
    #pragma unroll
    for (int x = 0; x < 3; ++x) {
        float s = 0.0f;
        #pragma unroll 4
        for (int c = 0; c < 64; ++c)
            s = fmaf(s3[w][x * 64 + c], W_ppx[c * 64 + l], s);
        pm[x] = s;
        sPm[w][x * 64 + l] = s;
    }
    __syncthreads();

    float dot = 0.0f;
    #pragma unroll
    for (int x = 0; x < 3; ++x) {
        float vi = 0.0f, vj = 0.0f;
        #pragma unroll 4
        for (int c = 0; c < 64; ++c) {
            float a = sPm[w][x * 64 + c];
            vi = fmaf(a, wi_dot[c * 64 + l], vi);
            vj = fmaf(a, wj_dot[c * 64 + l], vj);
        }
        dot = fmaf(vi, vj, dot);
    }

    sCat[w][l]      = pn;
    sCat[w][64 + l] = dot;
    __syncthreads();

    float u1 = b_pp1[l];
    float u2 = b_pp1[64 + l];
    #pragma unroll 4
    for (int k = 0; k < 128; ++k) {
        float ck = sCat[w][k];
        u1 = fmaf(ck, W_pp1[k * 128 + l], u1);
        u2 = fmaf(ck, W_pp1[k * 128 + 64 + l], u2);
    }
    float p1o = tanh_fast(u1);
    float s3v = tanh_fast(u2);

    out_p1[(size_t)n * 64 + l]  = p1o;
    out_dot[(size_t)n * 64 + l] = dot;
    #pragma unroll
    for (int x = 0; x < 3; ++x)
        out_p3[((size_t)n * 3 + x) * 64 + l] = pm[x] * s3v;
}

// ---------------------------------------------------------------------------
extern "C" void kernel_launch(void* const* d_in, const int* in_sizes, int n_in,
                              void* d_out, int out_size, void* d_ws, size_t ws_size,
                              hipStream_t stream)
{
    const int*   ind2   = (const int*)d_in[0];
    const float* p1     = (const float*)d_in[1];
    const float* p3     = (const float*)d_in[2];
    const float* d3     = (const float*)d_in[3];
    const float* basis  = (const float*)d_in[4];
    const float* W_pi   = (const float*)d_in[5];
    const float* b_pi   = (const float*)d_in[6];
    const float* W_ii   = (const float*)d_in[7];
    const float* W_pp   = (const float*)d_in[8];
    const float* wi_pix = (const float*)d_in[9];
    const float* wj_pix = (const float*)d_in[10];
    const float* W_ppx  = (const float*)d_in[11];
    const float* wi_dot = (const float*)d_in[12];
    const float* wj_dot = (const float*)d_in[13];
    const float* W_pp1  = (const float*)d_in[14];
    const float* b_pp1  = (const float*)d_in[15];

    float* out     = (float*)d_out;
    float* out_p1  = out;                      // 25000*64
    float* out_p3  = out + 1600000;            // 25000*192
    float* out_dot = out + 6400000;            // 25000*64
    float* out_i1  = out + 8000000;            // 500000*128
    float* out_ix  = out + 72000000;           // 500000*192

    // workspace (ws_size ~2.7GB; we use ~100MB)
    float*          u      = (float*)d_ws;                       // 6,400,000 f32
    unsigned short* v_bf   = (unsigned short*)(u + 6400000);     // 6,400,000 us
    unsigned short* qi_bf  = v_bf + 6400000;                     // 6,400,000 us
    unsigned short* qj_bf  = qi_bf + 6400000;                    // 6,400,000 us
    float*          p1_agg = (float*)(qj_bf + 6400000);          // 3,200,000 f32
    float*          p3_agg = p1_agg + 3200000;                   // 4,800,000 f32
    int*            cnt      = (int*)(p3_agg + 4800000);         // 25,000
    int*            rowstart = cnt + 25000;                      // 25,001
    int*            cursor   = rowstart + 25001;                 // 25,000
    int*            plist    = cursor + 25000;                   // 500,000

    hipMemsetAsync(cnt, 0, (size_t)75001 * sizeof(int), stream);

    dim3 blk(256);
    k0_uv    <<<dim3(6250), blk, 0, stream>>>(p1, W_pi, b_pi, u, v_bf);
    k0_q     <<<dim3(6250), blk, 0, stream>>>(p3, wi_pix, wj_pix, qi_bf, qj_bf);
    k_count  <<<dim3(1954), blk, 0, stream>>>(ind2, cnt);
    csr_scan <<<dim3(1), dim3(1024), 0, stream>>>(cnt, rowstart);
    k_scatter<<<dim3(1954), blk, 0, stream>>>(ind2, rowstart, cursor, plist);
    k_pair   <<<dim3(6250), blk, 0, stream>>>(ind2, d3, basis, W_ii, u, v_bf,
                                              qi_bf, qj_bf, rowstart, plist,
                                              out_i1, out_ix, p1_agg, p3_agg);
    k3_atoms <<<dim3(6250), blk, 0, stream>>>(p1_agg, p3_agg, W_pp, W_ppx,
                                              wi_dot, wj_dot, W_pp1, b_pp1,
                                              out_p1, out_p3, out_dot);
}

// Round 6
// 625.867 us; speedup vs baseline: 3.8334x; 1.1541x over previous
//
#include <hip/hip_runtime.h>

#define NP 500000
#define NA 25000

__device__ __forceinline__ float tanh_fast(float x) {
    float e = __expf(2.0f * x);
    return 1.0f - 2.0f / (e + 1.0f);
}

// readlane with float bitcast (__builtin_amdgcn_readlane is (int,int);
// passing float value-converts = truncates — the R2/R3 bug).
__device__ __forceinline__ float readlane_f(float v, int lane) {
    int iv = __builtin_bit_cast(int, v);
    int r = __builtin_amdgcn_readlane(iv, lane);
    return __builtin_bit_cast(float, r);
}

__device__ __forceinline__ unsigned short f2bf(float x) {
    union { float f; unsigned int u; } c; c.f = x;
    unsigned int r = c.u + 0x7FFFu + ((c.u >> 16) & 1u);
    return (unsigned short)(r >> 16);
}
__device__ __forceinline__ float bf2f(unsigned short h) {
    union { unsigned int u; float f; } c; c.u = ((unsigned int)h) << 16;
    return c.f;
}
__device__ __forceinline__ unsigned int pack2bf(float a, float b) {
    return (unsigned int)f2bf(a) | ((unsigned int)f2bf(b) << 16);
}
__device__ __forceinline__ float lo_bf(unsigned int x) { return bf2f((unsigned short)(x & 0xffffu)); }
__device__ __forceinline__ float hi_bf(unsigned int x) { return bf2f((unsigned short)(x >> 16)); }

// ---------------------------------------------------------------------------
// K0a: 16 atoms/block.  u = p1 @ W_pi[0:64,:] + b_pi  (f32 [atom][col])
//      v = p1 @ W_pi[64:128,:] -> vq[atom][l*8 + 0..3]  (bf16, col = 64q+l)
// ---------------------------------------------------------------------------
extern "C" __global__ __launch_bounds__(256, 2)
void k0_uv(const float* __restrict__ p1,
           const float* __restrict__ W_pi,
           const float* __restrict__ b_pi,
           float* __restrict__ u,
           unsigned short* __restrict__ vq)
{
    __shared__ float sW[32 * 256];     // 32 KB
    __shared__ float sp1[16 * 64];     //  4 KB

    const int t = threadIdx.x;
    const int wv = t >> 6;
    const int l = t & 63;
    const int atom0 = blockIdx.x * 16;

    #pragma unroll
    for (int f = 0; f < 4; ++f) {
        int idx = f * 256 + t;                  // 0..1023: atom = idx>>6, feat = idx&63
        int at = atom0 + (idx >> 6);
        int atc = at < NA ? at : NA - 1;
        sp1[idx] = p1[(size_t)atc * 64 + (idx & 63)];
    }

    float accu[4][4] = {{0}}, accv[4][4] = {{0}};

    #pragma unroll
    for (int s = 0; s < 4; ++s) {
        __syncthreads();
        {
            const float4* src = (const float4*)(W_pi + s * 32 * 256);
            float4* dst = (float4*)sW;
            #pragma unroll
            for (int f = 0; f < 8; ++f) dst[f * 256 + t] = src[f * 256 + t];
        }
        __syncthreads();
        const int kbase = (s & 1) * 32;
        #pragma unroll 2
        for (int k = 0; k < 32; ++k) {
            float wq[4];
            #pragma unroll
            for (int q = 0; q < 4; ++q) wq[q] = sW[k * 256 + 64 * q + l];
            #pragma unroll
            for (int a = 0; a < 4; ++a) {
                float pv = sp1[(wv * 4 + a) * 64 + kbase + k];
                #pragma unroll
                for (int q = 0; q < 4; ++q) {
                    if (s < 2) accu[a][q] = fmaf(pv, wq[q], accu[a][q]);
                    else       accv[a][q] = fmaf(pv, wq[q], accv[a][q]);
                }
            }
        }
    }

    #pragma unroll
    for (int a = 0; a < 4; ++a) {
        const int at = atom0 + wv * 4 + a;
        if (at < NA) {
            #pragma unroll
            for (int q = 0; q < 4; ++q)
                u[(size_t)at * 256 + 64 * q + l] = accu[a][q] + b_pi[64 * q + l];
            uint2 vv;
            vv.x = pack2bf(accv[a][0], accv[a][1]);
            vv.y = pack2bf(accv[a][2], accv[a][3]);
            *(uint2*)&vq[(size_t)at * 512 + 8 * l] = vv;
        }
    }
}

// ---------------------------------------------------------------------------
// K0b: qi = p3 @ wi_pix -> qi_bf[atom][4l+x];  qj = p3 @ wj_pix -> vq[atom][8l+4..6]
// wave per atom.
// ---------------------------------------------------------------------------
extern "C" __global__ __launch_bounds__(256, 4)
void k0_q(const float* __restrict__ p3,
          const float* __restrict__ wi_pix,
          const float* __restrict__ wj_pix,
          unsigned short* __restrict__ qi_bf,
          unsigned short* __restrict__ vq)
{
    __shared__ float sWi[64 * 64];
    __shared__ float sWj[64 * 64];

    const int t = threadIdx.x;
    {
        const float4* si = (const float4*)wi_pix;
        const float4* sj = (const float4*)wj_pix;
        float4* di = (float4*)sWi;
        float4* dj = (float4*)sWj;
        #pragma unroll
        for (int f = 0; f < 4; ++f) { di[f * 256 + t] = si[f * 256 + t]; dj[f * 256 + t] = sj[f * 256 + t]; }
    }
    __syncthreads();

    const int w = t >> 6;
    const int l = t & 63;
    const int atom = blockIdx.x * 4 + w;     // grid 6250 -> < 25000

    float val0 = p3[((size_t)atom * 3 + 0) * 64 + l];
    float val1 = p3[((size_t)atom * 3 + 1) * 64 + l];
    float val2 = p3[((size_t)atom * 3 + 2) * 64 + l];

    float ai[3] = {0, 0, 0}, aj[3] = {0, 0, 0};
    #pragma unroll 8
    for (int k = 0; k < 64; ++k) {
        float a0 = readlane_f(val0, k);
        float a1 = readlane_f(val1, k);
        float a2 = readlane_f(val2, k);
        float wi = sWi[k * 64 + l];
        float wj = sWj[k * 64 + l];
        ai[0] = fmaf(a0, wi, ai[0]); aj[0] = fmaf(a0, wj, aj[0]);
        ai[1] = fmaf(a1, wi, ai[1]); aj[1] = fmaf(a1, wj, aj[1]);
        ai[2] = fmaf(a2, wi, ai[2]); aj[2] = fmaf(a2, wj, aj[2]);
    }
    uint2 iu, ju;
    iu.x = pack2bf(ai[0], ai[1]); iu.y = pack2bf(ai[2], 0.0f);
    ju.x = pack2bf(aj[0], aj[1]); ju.y = pack2bf(aj[2], 0.0f);
    *(uint2*)&qi_bf[(size_t)atom * 256 + 4 * l] = iu;
    *(uint2*)&vq[(size_t)atom * 512 + 8 * l + 4] = ju;
}

// ---------------------------------------------------------------------------
// CSR build
// ---------------------------------------------------------------------------
extern "C" __global__ void k_count(const int* __restrict__ ind2, int* __restrict__ cnt)
{
    int p = blockIdx.x * 256 + threadIdx.x;
    if (p < NP) atomicAdd(&cnt[ind2[2 * p]], 1);
}

extern "C" __global__ __launch_bounds__(1024)
void csr_scan(const int* __restrict__ cnt, int* __restrict__ rowstart)
{
    __shared__ int ssum[1024];
    const int t = threadIdx.x;
    const int base = t * 25;

    int s = 0;
    #pragma unroll 5
    for (int i = 0; i < 25; ++i) {
        int idx = base + i;
        s += (idx < NA) ? cnt[idx] : 0;
    }
    ssum[t] = s;
    __syncthreads();
    for (int off = 1; off < 1024; off <<= 1) {
        int vv = (t >= off) ? ssum[t - off] : 0;
        __syncthreads();
        ssum[t] += vv;
        __syncthreads();
    }
    int run = (t > 0) ? ssum[t - 1] : 0;
    for (int i = 0; i < 25; ++i) {
        int idx = base + i;
        if (idx <= NA) rowstart[idx] = run;
        run += (idx < NA) ? cnt[idx] : 0;
    }
}

extern "C" __global__ void k_scatter(const int* __restrict__ ind2,
                                     const int* __restrict__ rowstart,
                                     int* __restrict__ cursor,
                                     int* __restrict__ plist)
{
    int p = blockIdx.x * 256 + threadIdx.x;
    if (p < NP) {
        int ii = ind2[2 * p];
        int pos = atomicAdd(&cursor[ii], 1);
        plist[rowstart[ii] + pos] = p;
    }
}

// ---------------------------------------------------------------------------
// K_pair: wave per atom; per pair ONE 16B gather (v|qj interleaved).
// 3-stage pipeline: A=compute, B=data in flight, C=indices in flight.
// ---------------------------------------------------------------------------
extern "C" __global__ __launch_bounds__(256, 3)
void k_pair(const int* __restrict__ ind2,
            const float* __restrict__ d3,
            const float* __restrict__ basis,
            const float* __restrict__ W_ii,
            const float* __restrict__ u,
            const unsigned short* __restrict__ vq,
            const unsigned short* __restrict__ qi_bf,
            const int* __restrict__ rowstart,
            const int* __restrict__ plist,
            float* __restrict__ out_i1,
            float* __restrict__ out_ix,
            float* __restrict__ p1_agg,
            float* __restrict__ p3_agg)
{
    const int t = threadIdx.x;
    const int w = t >> 6;
    const int l = t & 63;
    const int n = blockIdx.x * 4 + w;        // grid 6250*4 = 25000 exactly

    float wA[32], wB[32];
    #pragma unroll
    for (int c = 0; c < 32; ++c) {
        wA[c] = W_ii[c * 128 + l];
        wB[c] = W_ii[c * 128 + 64 + l];
    }

    float uu[4];
    #pragma unroll
    for (int q = 0; q < 4; ++q) uu[q] = u[(size_t)n * 256 + 64 * q + l];
    float qiv[3];
    {
        uint2 iu = *(const uint2*)&qi_bf[(size_t)n * 256 + 4 * l];
        qiv[0] = lo_bf(iu.x); qiv[1] = hi_bf(iu.x); qiv[2] = lo_bf(iu.y);
    }

    const int start = rowstart[n];
    const int end   = rowstart[n + 1];

    float agg1a = 0.0f, agg1b = 0.0f;
    float agg30 = 0.0f, agg31 = 0.0f, agg32 = 0.0f;

    if (start < end) {
        const int last = end - 1;

        int pA = plist[start];
        int jjA = ind2[2 * pA + 1];
        uint4 vqA = *(const uint4*)&vq[(size_t)jjA * 512 + 8 * l];
        float bsA = basis[(size_t)pA * 8 + (l & 7)];
        float dA0 = d3[3 * (size_t)pA + 0];
        float dA1 = d3[3 * (size_t)pA + 1];
        float dA2 = d3[3 * (size_t)pA + 2];

        int i1x = (start + 1 <= last) ? start + 1 : last;
        int pB = plist[i1x];
        int jjB = ind2[2 * pB + 1];
        uint4 vqB = *(const uint4*)&vq[(size_t)jjB * 512 + 8 * l];
        float bsB = basis[(size_t)pB * 8 + (l & 7)];
        float dB0 = d3[3 * (size_t)pB + 0];
        float dB1 = d3[3 * (size_t)pB + 1];
        float dB2 = d3[3 * (size_t)pB + 2];

        int i2x = (start + 2 <= last) ? start + 2 : last;
        int pC = plist[i2x];
        int jjC = ind2[2 * pC + 1];

        for (int it = start; it < end; ++it) {
            // issue stage-C data loads, stage-D index loads
            uint4 vqC = *(const uint4*)&vq[(size_t)jjC * 512 + 8 * l];
            float bsC = basis[(size_t)pC * 8 + (l & 7)];
            float dC0 = d3[3 * (size_t)pC + 0];
            float dC1 = d3[3 * (size_t)pC + 1];
            float dC2 = d3[3 * (size_t)pC + 2];
            int i3x = (it + 3 <= last) ? it + 3 : last;
            int pD = plist[i3x];
            int jjD = ind2[2 * pD + 1];

            // ---- compute with stage A ----
            float hq0 = tanh_fast(uu[0] + lo_bf(vqA.x));
            float hq1 = tanh_fast(uu[1] + hi_bf(vqA.x));
            float hq2 = tanh_fast(uu[2] + lo_bf(vqA.y));
            float hq3 = tanh_fast(uu[3] + hi_bf(vqA.y));

            float pre[4];
            {
                float s0 = hq0 * bsA, s1 = hq1 * bsA, s2 = hq2 * bsA, s3 = hq3 * bsA;
                s0 += __shfl_xor(s0, 1); s1 += __shfl_xor(s1, 1);
                s2 += __shfl_xor(s2, 1); s3 += __shfl_xor(s3, 1);
                s0 += __shfl_xor(s0, 2); s1 += __shfl_xor(s1, 2);
                s2 += __shfl_xor(s2, 2); s3 += __shfl_xor(s3, 2);
                s0 += __shfl_xor(s0, 4); s1 += __shfl_xor(s1, 4);
                s2 += __shfl_xor(s2, 4); s3 += __shfl_xor(s3, 4);
                pre[0] = s0; pre[1] = s1; pre[2] = s2; pre[3] = s3;
            }

            float a00 = 0, a01 = 0, a10 = 0, a11 = 0;
            #pragma unroll
            for (int c = 0; c < 32; c += 2) {
                float p0 = readlane_f(pre[c >> 3], 8 * (c & 7));
                float p1 = readlane_f(pre[(c + 1) >> 3], 8 * ((c + 1) & 7));
                a00 = fmaf(p0, wA[c], a00);     a10 = fmaf(p0, wB[c], a10);
                a01 = fmaf(p1, wA[c + 1], a01); a11 = fmaf(p1, wB[c + 1], a11);
            }
            const float i10 = tanh_fast(a00 + a01);
            const float i11 = tanh_fast(a10 + a11);

            __builtin_nontemporal_store(i10, &out_i1[(size_t)pA * 128 + l]);
            __builtin_nontemporal_store(i11, &out_i1[(size_t)pA * 128 + 64 + l]);
            agg1a += i10;
            agg1b += i11;

            float ix0 = (qiv[0] + lo_bf(vqA.z) + dA0) * i11;
            float ix1 = (qiv[1] + hi_bf(vqA.z) + dA1) * i11;
            float ix2 = (qiv[2] + lo_bf(vqA.w) + dA2) * i11;
            __builtin_nontemporal_store(ix0, &out_ix[((size_t)pA * 3 + 0) * 64 + l]);
            __builtin_nontemporal_store(ix1, &out_ix[((size_t)pA * 3 + 1) * 64 + l]);
            __builtin_nontemporal_store(ix2, &out_ix[((size_t)pA * 3 + 2) * 64 + l]);
            agg30 += ix0; agg31 += ix1; agg32 += ix2;

            // rotate stages
            pA = pB; vqA = vqB; bsA = bsB; dA0 = dB0; dA1 = dB1; dA2 = dB2;
            pB = pC; vqB = vqC; bsB = bsC; dB0 = dC0; dB1 = dC1; dB2 = dC2;
            pC = pD; jjC = jjD;
        }
    }

    p1_agg[(size_t)n * 128 + l]      = agg1a;
    p1_agg[(size_t)n * 128 + 64 + l] = agg1b;
    p3_agg[(size_t)n * 192 + l]       = agg30;
    p3_agg[(size_t)n * 192 + 64 + l]  = agg31;
    p3_agg[(size_t)n * 192 + 128 + l] = agg32;
}

// ---------------------------------------------------------------------------
// K3: per-atom tail.
// ---------------------------------------------------------------------------
extern "C" __global__ __launch_bounds__(256, 4)
void k3_atoms(const float* __restrict__ p1_agg,
              const float* __restrict__ p3_agg,
              const float* __restrict__ W_pp,
              const float* __restrict__ W_ppx,
              const float* __restrict__ wi_dot,
              const float* __restrict__ wj_dot,
              const float* __restrict__ W_pp1,
              const float* __restrict__ b_pp1,
              float* __restrict__ out_p1,
              float* __restrict__ out_p3,
              float* __restrict__ out_dot)
{
    __shared__ float s1[4][128];
    __shared__ float s3[4][192];
    __shared__ float sPm[4][192];
    __shared__ float sCat[4][128];

    const int w = threadIdx.x >> 6;
    const int l = threadIdx.x & 63;
    const int n = blockIdx.x * 4 + w;    // grid = 6250 exactly

    s1[w][l]      = p1_agg[(size_t)n * 128 + l];
    s1[w][64 + l] = p1_agg[(size_t)n * 128 + 64 + l];
    #pragma unroll
    for (int x = 0; x < 3; ++x)
        s3[w][x * 64 + l] = p3_agg[(size_t)n * 192 + x * 64 + l];
    __syncthreads();

    float pn = 0.0f;
    #pragma unroll 4
    for (int k = 0; k < 128; ++k)
        pn = fmaf(s1[w][k], W_pp[k * 64 + l], pn);
    pn = tanh_fast(pn);

    float pm[3];
    #pragma unroll
    for (int x = 0; x < 3; ++x) {
        float s = 0.0f;
        #pragma unroll 4
        for (int c = 0; c < 64; ++c)
            s = fmaf(s3[w][x * 64 + c], W_ppx[c * 64 + l], s);
        pm[x] = s;
        sPm[w][x * 64 + l] = s;
    }
    __syncthreads();

    float dot = 0.0f;
    #pragma unroll
    for (int x = 0; x < 3; ++x) {
        float vi = 0.0f, vj = 0.0f;
        #pragma unroll 4
        for (int c = 0; c < 64; ++c) {
            float a = sPm[w][x * 64 + c];
            vi = fmaf(a, wi_dot[c * 64 + l], vi);
            vj = fmaf(a, wj_dot[c * 64 + l], vj);
        }
        dot = fmaf(vi, vj, dot);
    }

    sCat[w][l]      = pn;
    sCat[w][64 + l] = dot;
    __syncthreads();

    float u1 = b_pp1[l];
    float u2 = b_pp1[64 + l];
    #pragma unroll 4
    for (int k = 0; k < 128; ++k) {
        float ck = sCat[w][k];
        u1 = fmaf(ck, W_pp1[k * 128 + l], u1);
        u2 = fmaf(ck, W_pp1[k * 128 + 64 + l], u2);
    }
    float p1o = tanh_fast(u1);
    float s3v = tanh_fast(u2);

    out_p1[(size_t)n * 64 + l]  = p1o;
    out_dot[(size_t)n * 64 + l] = dot;
    #pragma unroll
    for (int x = 0; x < 3; ++x)
        out_p3[((size_t)n * 3 + x) * 64 + l] = pm[x] * s3v;
}

// ---------------------------------------------------------------------------
extern "C" void kernel_launch(void* const* d_in, const int* in_sizes, int n_in,
                              void* d_out, int out_size, void* d_ws, size_t ws_size,
                              hipStream_t stream)
{
    const int*   ind2   = (const int*)d_in[0];
    const float* p1     = (const float*)d_in[1];
    const float* p3     = (const float*)d_in[2];
    const float* d3     = (const float*)d_in[3];
    const float* basis  = (const float*)d_in[4];
    const float* W_pi   = (const float*)d_in[5];
    const float* b_pi   = (const float*)d_in[6];
    const float* W_ii   = (const float*)d_in[7];
    const float* W_pp   = (const float*)d_in[8];
    const float* wi_pix = (const float*)d_in[9];
    const float* wj_pix = (const float*)d_in[10];
    const float* W_ppx  = (const float*)d_in[11];
    const float* wi_dot = (const float*)d_in[12];
    const float* wj_dot = (const float*)d_in[13];
    const float* W_pp1  = (const float*)d_in[14];
    const float* b_pp1  = (const float*)d_in[15];

    float* out     = (float*)d_out;
    float* out_p1  = out;                      // 25000*64
    float* out_p3  = out + 1600000;            // 25000*192
    float* out_dot = out + 6400000;            // 25000*64
    float* out_i1  = out + 8000000;            // 500000*128
    float* out_ix  = out + 72000000;           // 500000*192

    // workspace (~90MB of the ~2.7GB ws)
    float*          u      = (float*)d_ws;                       // 6,400,000 f32
    unsigned short* vq     = (unsigned short*)(u + 6400000);     // 12,800,000 us (v|qj interleaved)
    unsigned short* qi_bf  = vq + 12800000;                      // 6,400,000 us
    float*          p1_agg = (float*)(qi_bf + 6400000);          // 3,200,000 f32
    float*          p3_agg = p1_agg + 3200000;                   // 4,800,000 f32
    int*            cnt      = (int*)(p3_agg + 4800000);         // 25,000
    int*            rowstart = cnt + 25000;                      // 25,001
    int*            cursor   = rowstart + 25001;                 // 25,000
    int*            plist    = cursor + 25000;                   // 500,000

    hipMemsetAsync(cnt, 0, (size_t)75001 * sizeof(int), stream);

    dim3 blk(256);
    k0_uv    <<<dim3(1563), blk, 0, stream>>>(p1, W_pi, b_pi, u, vq);
    k0_q     <<<dim3(6250), blk, 0, stream>>>(p3, wi_pix, wj_pix, qi_bf, vq);
    k_count  <<<dim3(1954), blk, 0, stream>>>(ind2, cnt);
    csr_scan <<<dim3(1), dim3(1024), 0, stream>>>(cnt, rowstart);
    k_scatter<<<dim3(1954), blk, 0, stream>>>(ind2, rowstart, cursor, plist);
    k_pair   <<<dim3(6250), blk, 0, stream>>>(ind2, d3, basis, W_ii, u, vq,
                                              qi_bf, rowstart, plist,
                                              out_i1, out_ix, p1_agg, p3_agg);
    k3_atoms <<<dim3(6250), blk, 0, stream>>>(p1_agg, p3_agg, W_pp, W_ppx,
                                              wi_dot, wj_dot, W_pp1, b_pp1,
                                              out_p1, out_p3, out_dot);
}

// Round 7
// 611.358 us; speedup vs baseline: 3.9244x; 1.0237x over previous
//
#include <hip/hip_runtime.h>

#define NP 500000
#define NA 25000

__device__ __forceinline__ float tanh_fast(float x) {
    float e = __expf(2.0f * x);
    return 1.0f - 2.0f / (e + 1.0f);
}

// readlane with float bitcast (__builtin_amdgcn_readlane is (int,int);
// passing float value-converts = truncates — the R2/R3 bug).
__device__ __forceinline__ float readlane_f(float v, int lane) {
    int iv = __builtin_bit_cast(int, v);
    int r = __builtin_amdgcn_readlane(iv, lane);
    return __builtin_bit_cast(float, r);
}

// Sum over each consecutive 8-lane group, all in VALU (DPP), no LDS:
// xor1 = quad_perm(1,0,3,2)=0xB1, xor2 = quad_perm(2,3,0,1)=0x4E,
// then row_half_mirror(0x141): lane i adds lane (7-i) of its 8-group,
// which holds the other quad's (identical) quad-sum — bit-identical to
// the shfl_xor(4) step.
__device__ __forceinline__ float dpp8_reduce(float s) {
    int x;
    x = __builtin_amdgcn_update_dpp(0, __builtin_bit_cast(int, s), 0xB1, 0xF, 0xF, true);
    s += __builtin_bit_cast(float, x);
    x = __builtin_amdgcn_update_dpp(0, __builtin_bit_cast(int, s), 0x4E, 0xF, 0xF, true);
    s += __builtin_bit_cast(float, x);
    x = __builtin_amdgcn_update_dpp(0, __builtin_bit_cast(int, s), 0x141, 0xF, 0xF, true);
    s += __builtin_bit_cast(float, x);
    return s;
}

__device__ __forceinline__ unsigned short f2bf(float x) {
    union { float f; unsigned int u; } c; c.f = x;
    unsigned int r = c.u + 0x7FFFu + ((c.u >> 16) & 1u);
    return (unsigned short)(r >> 16);
}
__device__ __forceinline__ float bf2f(unsigned short h) {
    union { unsigned int u; float f; } c; c.u = ((unsigned int)h) << 16;
    return c.f;
}
__device__ __forceinline__ unsigned int pack2bf(float a, float b) {
    return (unsigned int)f2bf(a) | ((unsigned int)f2bf(b) << 16);
}
__device__ __forceinline__ float lo_bf(unsigned int x) { return bf2f((unsigned short)(x & 0xffffu)); }
__device__ __forceinline__ float hi_bf(unsigned int x) { return bf2f((unsigned short)(x >> 16)); }

// ---------------------------------------------------------------------------
// K0a: 16 atoms/block.  u = p1 @ W_pi[0:64,:] + b_pi  (f32 [atom][col])
//      v = p1 @ W_pi[64:128,:] -> vq[atom][l*8 + 0..3]  (bf16, col = 64q+l)
// ---------------------------------------------------------------------------
extern "C" __global__ __launch_bounds__(256, 2)
void k0_uv(const float* __restrict__ p1,
           const float* __restrict__ W_pi,
           const float* __restrict__ b_pi,
           float* __restrict__ u,
           unsigned short* __restrict__ vq)
{
    __shared__ float sW[32 * 256];     // 32 KB
    __shared__ float sp1[16 * 64];     //  4 KB

    const int t = threadIdx.x;
    const int wv = t >> 6;
    const int l = t & 63;
    const int atom0 = blockIdx.x * 16;

    #pragma unroll
    for (int f = 0; f < 4; ++f) {
        int idx = f * 256 + t;
        int at = atom0 + (idx >> 6);
        int atc = at < NA ? at : NA - 1;
        sp1[idx] = p1[(size_t)atc * 64 + (idx & 63)];
    }

    float accu[4][4] = {{0}}, accv[4][4] = {{0}};

    #pragma unroll
    for (int s = 0; s < 4; ++s) {
        __syncthreads();
        {
            const float4* src = (const float4*)(W_pi + s * 32 * 256);
            float4* dst = (float4*)sW;
            #pragma unroll
            for (int f = 0; f < 8; ++f) dst[f * 256 + t] = src[f * 256 + t];
        }
        __syncthreads();
        const int kbase = (s & 1) * 32;
        #pragma unroll 2
        for (int k = 0; k < 32; ++k) {
            float wq[4];
            #pragma unroll
            for (int q = 0; q < 4; ++q) wq[q] = sW[k * 256 + 64 * q + l];
            #pragma unroll
            for (int a = 0; a < 4; ++a) {
                float pv = sp1[(wv * 4 + a) * 64 + kbase + k];
                #pragma unroll
                for (int q = 0; q < 4; ++q) {
                    if (s < 2) accu[a][q] = fmaf(pv, wq[q], accu[a][q]);
                    else       accv[a][q] = fmaf(pv, wq[q], accv[a][q]);
                }
            }
        }
    }

    #pragma unroll
    for (int a = 0; a < 4; ++a) {
        const int at = atom0 + wv * 4 + a;
        if (at < NA) {
            #pragma unroll
            for (int q = 0; q < 4; ++q)
                u[(size_t)at * 256 + 64 * q + l] = accu[a][q] + b_pi[64 * q + l];
            uint2 vv;
            vv.x = pack2bf(accv[a][0], accv[a][1]);
            vv.y = pack2bf(accv[a][2], accv[a][3]);
            *(uint2*)&vq[(size_t)at * 512 + 8 * l] = vv;
        }
    }
}

// ---------------------------------------------------------------------------
// K0b: qi = p3 @ wi_pix -> qi_bf[atom][4l+x];  qj = p3 @ wj_pix -> vq[atom][8l+4..6]
// wave per atom.
// ---------------------------------------------------------------------------
extern "C" __global__ __launch_bounds__(256, 4)
void k0_q(const float* __restrict__ p3,
          const float* __restrict__ wi_pix,
          const float* __restrict__ wj_pix,
          unsigned short* __restrict__ qi_bf,
          unsigned short* __restrict__ vq)
{
    __shared__ float sWi[64 * 64];
    __shared__ float sWj[64 * 64];

    const int t = threadIdx.x;
    {
        const float4* si = (const float4*)wi_pix;
        const float4* sj = (const float4*)wj_pix;
        float4* di = (float4*)sWi;
        float4* dj = (float4*)sWj;
        #pragma unroll
        for (int f = 0; f < 4; ++f) { di[f * 256 + t] = si[f * 256 + t]; dj[f * 256 + t] = sj[f * 256 + t]; }
    }
    __syncthreads();

    const int w = t >> 6;
    const int l = t & 63;
    const int atom = blockIdx.x * 4 + w;     // grid 6250 -> < 25000

    float val0 = p3[((size_t)atom * 3 + 0) * 64 + l];
    float val1 = p3[((size_t)atom * 3 + 1) * 64 + l];
    float val2 = p3[((size_t)atom * 3 + 2) * 64 + l];

    float ai[3] = {0, 0, 0}, aj[3] = {0, 0, 0};
    #pragma unroll 8
    for (int k = 0; k < 64; ++k) {
        float a0 = readlane_f(val0, k);
        float a1 = readlane_f(val1, k);
        float a2 = readlane_f(val2, k);
        float wi = sWi[k * 64 + l];
        float wj = sWj[k * 64 + l];
        ai[0] = fmaf(a0, wi, ai[0]); aj[0] = fmaf(a0, wj, aj[0]);
        ai[1] = fmaf(a1, wi, ai[1]); aj[1] = fmaf(a1, wj, aj[1]);
        ai[2] = fmaf(a2, wi, ai[2]); aj[2] = fmaf(a2, wj, aj[2]);
    }
    uint2 iu, ju;
    iu.x = pack2bf(ai[0], ai[1]); iu.y = pack2bf(ai[2], 0.0f);
    ju.x = pack2bf(aj[0], aj[1]); ju.y = pack2bf(aj[2], 0.0f);
    *(uint2*)&qi_bf[(size_t)atom * 256 + 4 * l] = iu;
    *(uint2*)&vq[(size_t)atom * 512 + 8 * l + 4] = ju;
}

// ---------------------------------------------------------------------------
// CSR build
// ---------------------------------------------------------------------------
extern "C" __global__ void k_count(const int* __restrict__ ind2, int* __restrict__ cnt)
{
    int p = blockIdx.x * 256 + threadIdx.x;
    if (p < NP) atomicAdd(&cnt[ind2[2 * p]], 1);
}

extern "C" __global__ __launch_bounds__(1024)
void csr_scan(const int* __restrict__ cnt, int* __restrict__ rowstart)
{
    __shared__ int ssum[1024];
    const int t = threadIdx.x;
    const int base = t * 25;

    int s = 0;
    #pragma unroll 5
    for (int i = 0; i < 25; ++i) {
        int idx = base + i;
        s += (idx < NA) ? cnt[idx] : 0;
    }
    ssum[t] = s;
    __syncthreads();
    for (int off = 1; off < 1024; off <<= 1) {
        int vv = (t >= off) ? ssum[t - off] : 0;
        __syncthreads();
        ssum[t] += vv;
        __syncthreads();
    }
    int run = (t > 0) ? ssum[t - 1] : 0;
    for (int i = 0; i < 25; ++i) {
        int idx = base + i;
        if (idx <= NA) rowstart[idx] = run;
        run += (idx < NA) ? cnt[idx] : 0;
    }
}

extern "C" __global__ void k_scatter(const int* __restrict__ ind2,
                                     const int* __restrict__ rowstart,
                                     int* __restrict__ cursor,
                                     int* __restrict__ plist)
{
    int p = blockIdx.x * 256 + threadIdx.x;
    if (p < NP) {
        int ii = ind2[2 * p];
        int pos = atomicAdd(&cursor[ii], 1);
        plist[rowstart[ii] + pos] = p;
    }
}

// ---------------------------------------------------------------------------
// K_pair: wave per atom; per pair ONE 16B gather (v|qj interleaved).
// 3-stage pipeline; 8-lane basis reduction via DPP (pure VALU, no LDS).
// ---------------------------------------------------------------------------
extern "C" __global__ __launch_bounds__(256, 3)
void k_pair(const int* __restrict__ ind2,
            const float* __restrict__ d3,
            const float* __restrict__ basis,
            const float* __restrict__ W_ii,
            const float* __restrict__ u,
            const unsigned short* __restrict__ vq,
            const unsigned short* __restrict__ qi_bf,
            const int* __restrict__ rowstart,
            const int* __restrict__ plist,
            float* __restrict__ out_i1,
            float* __restrict__ out_ix,
            float* __restrict__ p1_agg,
            float* __restrict__ p3_agg)
{
    const int t = threadIdx.x;
    const int w = t >> 6;
    const int l = t & 63;
    const int n = blockIdx.x * 4 + w;        // grid 6250*4 = 25000 exactly

    float wA[32], wB[32];
    #pragma unroll
    for (int c = 0; c < 32; ++c) {
        wA[c] = W_ii[c * 128 + l];
        wB[c] = W_ii[c * 128 + 64 + l];
    }

    float uu[4];
    #pragma unroll
    for (int q = 0; q < 4; ++q) uu[q] = u[(size_t)n * 256 + 64 * q + l];
    float qiv[3];
    {
        uint2 iu = *(const uint2*)&qi_bf[(size_t)n * 256 + 4 * l];
        qiv[0] = lo_bf(iu.x); qiv[1] = hi_bf(iu.x); qiv[2] = lo_bf(iu.y);
    }

    const int start = rowstart[n];
    const int end   = rowstart[n + 1];

    float agg1a = 0.0f, agg1b = 0.0f;
    float agg30 = 0.0f, agg31 = 0.0f, agg32 = 0.0f;

    if (start < end) {
        const int last = end - 1;

        int pA = plist[start];
        int jjA = ind2[2 * pA + 1];
        uint4 vqA = *(const uint4*)&vq[(size_t)jjA * 512 + 8 * l];
        float bsA = basis[(size_t)pA * 8 + (l & 7)];
        float dA0 = d3[3 * (size_t)pA + 0];
        float dA1 = d3[3 * (size_t)pA + 1];
        float dA2 = d3[3 * (size_t)pA + 2];

        int i1x = (start + 1 <= last) ? start + 1 : last;
        int pB = plist[i1x];
        int jjB = ind2[2 * pB + 1];
        uint4 vqB = *(const uint4*)&vq[(size_t)jjB * 512 + 8 * l];
        float bsB = basis[(size_t)pB * 8 + (l & 7)];
        float dB0 = d3[3 * (size_t)pB + 0];
        float dB1 = d3[3 * (size_t)pB + 1];
        float dB2 = d3[3 * (size_t)pB + 2];

        int i2x = (start + 2 <= last) ? start + 2 : last;
        int pC = plist[i2x];
        int jjC = ind2[2 * pC + 1];

        for (int it = start; it < end; ++it) {
            // issue stage-C data loads, stage-D index loads
            uint4 vqC = *(const uint4*)&vq[(size_t)jjC * 512 + 8 * l];
            float bsC = basis[(size_t)pC * 8 + (l & 7)];
            float dC0 = d3[3 * (size_t)pC + 0];
            float dC1 = d3[3 * (size_t)pC + 1];
            float dC2 = d3[3 * (size_t)pC + 2];
            int i3x = (it + 3 <= last) ? it + 3 : last;
            int pD = plist[i3x];
            int jjD = ind2[2 * pD + 1];

            // ---- compute with stage A ----
            float hq0 = tanh_fast(uu[0] + lo_bf(vqA.x));
            float hq1 = tanh_fast(uu[1] + hi_bf(vqA.x));
            float hq2 = tanh_fast(uu[2] + lo_bf(vqA.y));
            float hq3 = tanh_fast(uu[3] + hi_bf(vqA.y));

            float pre[4];
            pre[0] = dpp8_reduce(hq0 * bsA);
            pre[1] = dpp8_reduce(hq1 * bsA);
            pre[2] = dpp8_reduce(hq2 * bsA);
            pre[3] = dpp8_reduce(hq3 * bsA);

            float a00 = 0, a01 = 0, a10 = 0, a11 = 0;
            #pragma unroll
            for (int c = 0; c < 32; c += 2) {
                float p0 = readlane_f(pre[c >> 3], 8 * (c & 7));
                float p1 = readlane_f(pre[(c + 1) >> 3], 8 * ((c + 1) & 7));
                a00 = fmaf(p0, wA[c], a00);     a10 = fmaf(p0, wB[c], a10);
                a01 = fmaf(p1, wA[c + 1], a01); a11 = fmaf(p1, wB[c + 1], a11);
            }
            const float i10 = tanh_fast(a00 + a01);
            const float i11 = tanh_fast(a10 + a11);

            __builtin_nontemporal_store(i10, &out_i1[(size_t)pA * 128 + l]);
            __builtin_nontemporal_store(i11, &out_i1[(size_t)pA * 128 + 64 + l]);
            agg1a += i10;
            agg1b += i11;

            float ix0 = (qiv[0] + lo_bf(vqA.z) + dA0) * i11;
            float ix1 = (qiv[1] + hi_bf(vqA.z) + dA1) * i11;
            float ix2 = (qiv[2] + lo_bf(vqA.w) + dA2) * i11;
            __builtin_nontemporal_store(ix0, &out_ix[((size_t)pA * 3 + 0) * 64 + l]);
            __builtin_nontemporal_store(ix1, &out_ix[((size_t)pA * 3 + 1) * 64 + l]);
            __builtin_nontemporal_store(ix2, &out_ix[((size_t)pA * 3 + 2) * 64 + l]);
            agg30 += ix0; agg31 += ix1; agg32 += ix2;

            // rotate stages
            pA = pB; vqA = vqB; bsA = bsB; dA0 = dB0; dA1 = dB1; dA2 = dB2;
            pB = pC; vqB = vqC; bsB = bsC; dB0 = dC0; dB1 = dC1; dB2 = dC2;
            pC = pD; jjC = jjD;
        }
    }

    p1_agg[(size_t)n * 128 + l]      = agg1a;
    p1_agg[(size_t)n * 128 + 64 + l] = agg1b;
    p3_agg[(size_t)n * 192 + l]       = agg30;
    p3_agg[(size_t)n * 192 + 64 + l]  = agg31;
    p3_agg[(size_t)n * 192 + 128 + l] = agg32;
}

// ---------------------------------------------------------------------------
// K3: per-atom tail.
// ---------------------------------------------------------------------------
extern "C" __global__ __launch_bounds__(256, 4)
void k3_atoms(const float* __restrict__ p1_agg,
              const float* __restrict__ p3_agg,
              const float* __restrict__ W_pp,
              const float* __restrict__ W_ppx,
              const float* __restrict__ wi_dot,
              const float* __restrict__ wj_dot,
              const float* __restrict__ W_pp1,
              const float* __restrict__ b_pp1,
              float* __restrict__ out_p1,
              float* __restrict__ out_p3,
              float* __restrict__ out_dot)
{
    __shared__ float s1[4][128];
    __shared__ float s3[4][192];
    __shared__ float sPm[4][192];
    __shared__ float sCat[4][128];

    const int w = threadIdx.x >> 6;
    const int l = threadIdx.x & 63;
    const int n = blockIdx.x * 4 + w;    // grid = 6250 exactly

    s1[w][l]      = p1_agg[(size_t)n * 128 + l];
    s1[w][64 + l] = p1_agg[(size_t)n * 128 + 64 + l];
    #pragma unroll
    for (int x = 0; x < 3; ++x)
        s3[w][x * 64 + l] = p3_agg[(size_t)n * 192 + x * 64 + l];
    __syncthreads();

    float pn = 0.0f;
    #pragma unroll 4
    for (int k = 0; k < 128; ++k)
        pn = fmaf(s1[w][k], W_pp[k * 64 + l], pn);
    pn = tanh_fast(pn);

    float pm[3];
    #pragma unroll
    for (int x = 0; x < 3; ++x) {
        float s = 0.0f;
        #pragma unroll 4
        for (int c = 0; c < 64; ++c)
            s = fmaf(s3[w][x * 64 + c], W_ppx[c * 64 + l], s);
        pm[x] = s;
        sPm[w][x * 64 + l] = s;
    }
    __syncthreads();

    float dot = 0.0f;
    #pragma unroll
    for (int x = 0; x < 3; ++x) {
        float vi = 0.0f, vj = 0.0f;
        #pragma unroll 4
        for (int c = 0; c < 64; ++c) {
            float a = sPm[w][x * 64 + c];
            vi = fmaf(a, wi_dot[c * 64 + l], vi);
            vj = fmaf(a, wj_dot[c * 64 + l], vj);
        }
        dot = fmaf(vi, vj, dot);
    }

    sCat[w][l]      = pn;
    sCat[w][64 + l] = dot;
    __syncthreads();

    float u1 = b_pp1[l];
    float u2 = b_pp1[64 + l];
    #pragma unroll 4
    for (int k = 0; k < 128; ++k) {
        float ck = sCat[w][k];
        u1 = fmaf(ck, W_pp1[k * 128 + l], u1);
        u2 = fmaf(ck, W_pp1[k * 128 + 64 + l], u2);
    }
    float p1o = tanh_fast(u1);
    float s3v = tanh_fast(u2);

    out_p1[(size_t)n * 64 + l]  = p1o;
    out_dot[(size_t)n * 64 + l] = dot;
    #pragma unroll
    for (int x = 0; x < 3; ++x)
        out_p3[((size_t)n * 3 + x) * 64 + l] = pm[x] * s3v;
}

// ---------------------------------------------------------------------------
extern "C" void kernel_launch(void* const* d_in, const int* in_sizes, int n_in,
                              void* d_out, int out_size, void* d_ws, size_t ws_size,
                              hipStream_t stream)
{
    const int*   ind2   = (const int*)d_in[0];
    const float* p1     = (const float*)d_in[1];
    const float* p3     = (const float*)d_in[2];
    const float* d3     = (const float*)d_in[3];
    const float* basis  = (const float*)d_in[4];
    const float* W_pi   = (const float*)d_in[5];
    const float* b_pi   = (const float*)d_in[6];
    const float* W_ii   = (const float*)d_in[7];
    const float* W_pp   = (const float*)d_in[8];
    const float* wi_pix = (const float*)d_in[9];
    const float* wj_pix = (const float*)d_in[10];
    const float* W_ppx  = (const float*)d_in[11];
    const float* wi_dot = (const float*)d_in[12];
    const float* wj_dot = (const float*)d_in[13];
    const float* W_pp1  = (const float*)d_in[14];
    const float* b_pp1  = (const float*)d_in[15];

    float* out     = (float*)d_out;
    float* out_p1  = out;                      // 25000*64
    float* out_p3  = out + 1600000;            // 25000*192
    float* out_dot = out + 6400000;            // 25000*64
    float* out_i1  = out + 8000000;            // 500000*128
    float* out_ix  = out + 72000000;           // 500000*192

    // workspace (~90MB of the ~2.7GB ws)
    float*          u      = (float*)d_ws;                       // 6,400,000 f32
    unsigned short* vq     = (unsigned short*)(u + 6400000);     // 12,800,000 us (v|qj interleaved)
    unsigned short* qi_bf  = vq + 12800000;                      // 6,400,000 us
    float*          p1_agg = (float*)(qi_bf + 6400000);          // 3,200,000 f32
    float*          p3_agg = p1_agg + 3200000;                   // 4,800,000 f32
    int*            cnt      = (int*)(p3_agg + 4800000);         // 25,000
    int*            rowstart = cnt + 25000;                      // 25,001
    int*            cursor   = rowstart + 25001;                 // 25,000
    int*            plist    = cursor + 25000;                   // 500,000

    hipMemsetAsync(cnt, 0, (size_t)75001 * sizeof(int), stream);

    dim3 blk(256);
    k0_uv    <<<dim3(1563), blk, 0, stream>>>(p1, W_pi, b_pi, u, vq);
    k0_q     <<<dim3(6250), blk, 0, stream>>>(p3, wi_pix, wj_pix, qi_bf, vq);
    k_count  <<<dim3(1954), blk, 0, stream>>>(ind2, cnt);
    csr_scan <<<dim3(1), dim3(1024), 0, stream>>>(cnt, rowstart);
    k_scatter<<<dim3(1954), blk, 0, stream>>>(ind2, rowstart, cursor, plist);
    k_pair   <<<dim3(6250), blk, 0, stream>>>(ind2, d3, basis, W_ii, u, vq,
                                              qi_bf, rowstart, plist,
                                              out_i1, out_ix, p1_agg, p3_agg);
    k3_atoms <<<dim3(6250), blk, 0, stream>>>(p1_agg, p3_agg, W_pp, W_ppx,
                                              wi_dot, wj_dot, W_pp1, b_pp1,
                                              out_p1, out_p3, out_dot);
}

// Round 8
// 602.863 us; speedup vs baseline: 3.9797x; 1.0141x over previous
//
#include <hip/hip_runtime.h>

#define NP 500000
#define NA 25000

__device__ __forceinline__ float tanh_fast(float x) {
    float e = __expf(2.0f * x);
    return 1.0f - 2.0f / (e + 1.0f);
}

// readlane with float bitcast (__builtin_amdgcn_readlane is (int,int);
// passing float value-converts = truncates — the R2/R3 bug).
__device__ __forceinline__ float readlane_f(float v, int lane) {
    int iv = __builtin_bit_cast(int, v);
    int r = __builtin_amdgcn_readlane(iv, lane);
    return __builtin_bit_cast(float, r);
}

// Sum over each consecutive 8-lane group, all in VALU (DPP), no LDS.
__device__ __forceinline__ float dpp8_reduce(float s) {
    int x;
    x = __builtin_amdgcn_update_dpp(0, __builtin_bit_cast(int, s), 0xB1, 0xF, 0xF, true);
    s += __builtin_bit_cast(float, x);
    x = __builtin_amdgcn_update_dpp(0, __builtin_bit_cast(int, s), 0x4E, 0xF, 0xF, true);
    s += __builtin_bit_cast(float, x);
    x = __builtin_amdgcn_update_dpp(0, __builtin_bit_cast(int, s), 0x141, 0xF, 0xF, true);
    s += __builtin_bit_cast(float, x);
    return s;
}

__device__ __forceinline__ unsigned short f2bf(float x) {
    union { float f; unsigned int u; } c; c.f = x;
    unsigned int r = c.u + 0x7FFFu + ((c.u >> 16) & 1u);
    return (unsigned short)(r >> 16);
}
__device__ __forceinline__ float bf2f(unsigned short h) {
    union { unsigned int u; float f; } c; c.u = ((unsigned int)h) << 16;
    return c.f;
}
__device__ __forceinline__ unsigned int pack2bf(float a, float b) {
    return (unsigned int)f2bf(a) | ((unsigned int)f2bf(b) << 16);
}
__device__ __forceinline__ float lo_bf(unsigned int x) { return bf2f((unsigned short)(x & 0xffffu)); }
__device__ __forceinline__ float hi_bf(unsigned int x) { return bf2f((unsigned short)(x >> 16)); }
// unpack a (lo,hi) bf16 pair to two f32 with 1 shift + 1 and
__device__ __forceinline__ float lo_bf_f(unsigned int x) {
    return __builtin_bit_cast(float, x << 16);
}
__device__ __forceinline__ float hi_bf_f(unsigned int x) {
    return __builtin_bit_cast(float, x & 0xffff0000u);
}

// ---------------------------------------------------------------------------
// K0a: 16 atoms/block.  u = p1 @ W_pi[0:64,:] + b_pi  (f32 [atom][col])
//      v = p1 @ W_pi[64:128,:] -> vq[atom][l*8 + 0..3]  (bf16, col = 64q+l)
// ---------------------------------------------------------------------------
extern "C" __global__ __launch_bounds__(256, 2)
void k0_uv(const float* __restrict__ p1,
           const float* __restrict__ W_pi,
           const float* __restrict__ b_pi,
           float* __restrict__ u,
           unsigned short* __restrict__ vq)
{
    __shared__ float sW[32 * 256];     // 32 KB
    __shared__ float sp1[16 * 64];     //  4 KB

    const int t = threadIdx.x;
    const int wv = t >> 6;
    const int l = t & 63;
    const int atom0 = blockIdx.x * 16;

    #pragma unroll
    for (int f = 0; f < 4; ++f) {
        int idx = f * 256 + t;
        int at = atom0 + (idx >> 6);
        int atc = at < NA ? at : NA - 1;
        sp1[idx] = p1[(size_t)atc * 64 + (idx & 63)];
    }

    float accu[4][4] = {{0}}, accv[4][4] = {{0}};

    #pragma unroll
    for (int s = 0; s < 4; ++s) {
        __syncthreads();
        {
            const float4* src = (const float4*)(W_pi + s * 32 * 256);
            float4* dst = (float4*)sW;
            #pragma unroll
            for (int f = 0; f < 8; ++f) dst[f * 256 + t] = src[f * 256 + t];
        }
        __syncthreads();
        const int kbase = (s & 1) * 32;
        #pragma unroll 2
        for (int k = 0; k < 32; ++k) {
            float wq[4];
            #pragma unroll
            for (int q = 0; q < 4; ++q) wq[q] = sW[k * 256 + 64 * q + l];
            #pragma unroll
            for (int a = 0; a < 4; ++a) {
                float pv = sp1[(wv * 4 + a) * 64 + kbase + k];
                #pragma unroll
                for (int q = 0; q < 4; ++q) {
                    if (s < 2) accu[a][q] = fmaf(pv, wq[q], accu[a][q]);
                    else       accv[a][q] = fmaf(pv, wq[q], accv[a][q]);
                }
            }
        }
    }

    #pragma unroll
    for (int a = 0; a < 4; ++a) {
        const int at = atom0 + wv * 4 + a;
        if (at < NA) {
            #pragma unroll
            for (int q = 0; q < 4; ++q)
                u[(size_t)at * 256 + 64 * q + l] = accu[a][q] + b_pi[64 * q + l];
            uint2 vv;
            vv.x = pack2bf(accv[a][0], accv[a][1]);
            vv.y = pack2bf(accv[a][2], accv[a][3]);
            *(uint2*)&vq[(size_t)at * 512 + 8 * l] = vv;
        }
    }
}

// ---------------------------------------------------------------------------
// K0b: qi = p3 @ wi_pix -> qi_bf[atom][4l+x];  qj = p3 @ wj_pix -> vq[atom][8l+4..6]
// ---------------------------------------------------------------------------
extern "C" __global__ __launch_bounds__(256, 4)
void k0_q(const float* __restrict__ p3,
          const float* __restrict__ wi_pix,
          const float* __restrict__ wj_pix,
          unsigned short* __restrict__ qi_bf,
          unsigned short* __restrict__ vq)
{
    __shared__ float sWi[64 * 64];
    __shared__ float sWj[64 * 64];

    const int t = threadIdx.x;
    {
        const float4* si = (const float4*)wi_pix;
        const float4* sj = (const float4*)wj_pix;
        float4* di = (float4*)sWi;
        float4* dj = (float4*)sWj;
        #pragma unroll
        for (int f = 0; f < 4; ++f) { di[f * 256 + t] = si[f * 256 + t]; dj[f * 256 + t] = sj[f * 256 + t]; }
    }
    __syncthreads();

    const int w = t >> 6;
    const int l = t & 63;
    const int atom = blockIdx.x * 4 + w;     // grid 6250 -> < 25000

    float val0 = p3[((size_t)atom * 3 + 0) * 64 + l];
    float val1 = p3[((size_t)atom * 3 + 1) * 64 + l];
    float val2 = p3[((size_t)atom * 3 + 2) * 64 + l];

    float ai[3] = {0, 0, 0}, aj[3] = {0, 0, 0};
    #pragma unroll 8
    for (int k = 0; k < 64; ++k) {
        float a0 = readlane_f(val0, k);
        float a1 = readlane_f(val1, k);
        float a2 = readlane_f(val2, k);
        float wi = sWi[k * 64 + l];
        float wj = sWj[k * 64 + l];
        ai[0] = fmaf(a0, wi, ai[0]); aj[0] = fmaf(a0, wj, aj[0]);
        ai[1] = fmaf(a1, wi, ai[1]); aj[1] = fmaf(a1, wj, aj[1]);
        ai[2] = fmaf(a2, wi, ai[2]); aj[2] = fmaf(a2, wj, aj[2]);
    }
    uint2 iu, ju;
    iu.x = pack2bf(ai[0], ai[1]); iu.y = pack2bf(ai[2], 0.0f);
    ju.x = pack2bf(aj[0], aj[1]); ju.y = pack2bf(aj[2], 0.0f);
    *(uint2*)&qi_bf[(size_t)atom * 256 + 4 * l] = iu;
    *(uint2*)&vq[(size_t)atom * 512 + 8 * l + 4] = ju;
}

// ---------------------------------------------------------------------------
// CSR build
// ---------------------------------------------------------------------------
extern "C" __global__ void k_count(const int* __restrict__ ind2, int* __restrict__ cnt)
{
    int p = blockIdx.x * 256 + threadIdx.x;
    if (p < NP) atomicAdd(&cnt[ind2[2 * p]], 1);
}

extern "C" __global__ __launch_bounds__(1024)
void csr_scan(const int* __restrict__ cnt, int* __restrict__ rowstart)
{
    __shared__ int ssum[1024];
    const int t = threadIdx.x;
    const int base = t * 25;

    int s = 0;
    #pragma unroll 5
    for (int i = 0; i < 25; ++i) {
        int idx = base + i;
        s += (idx < NA) ? cnt[idx] : 0;
    }
    ssum[t] = s;
    __syncthreads();
    for (int off = 1; off < 1024; off <<= 1) {
        int vv = (t >= off) ? ssum[t - off] : 0;
        __syncthreads();
        ssum[t] += vv;
        __syncthreads();
    }
    int run = (t > 0) ? ssum[t - 1] : 0;
    for (int i = 0; i < 25; ++i) {
        int idx = base + i;
        if (idx <= NA) rowstart[idx] = run;
        run += (idx < NA) ? cnt[idx] : 0;
    }
}

extern "C" __global__ void k_scatter(const int* __restrict__ ind2,
                                     const int* __restrict__ rowstart,
                                     int* __restrict__ cursor,
                                     int2* __restrict__ plist2)
{
    int p = blockIdx.x * 256 + threadIdx.x;
    if (p < NP) {
        int ii = ind2[2 * p];
        int jj = ind2[2 * p + 1];
        int pos = atomicAdd(&cursor[ii], 1);
        plist2[rowstart[ii] + pos] = make_int2(p, jj);
    }
}

// ---------------------------------------------------------------------------
// K_pair: wave per atom; per pair ONE 16B gather (v|qj interleaved).
// plist carries (p, jj) — no dependent ind2 load. W_ii packed bf16 (32 VGPR).
// 3-stage pipeline; 8-lane basis reduction via DPP. 4 waves/SIMD.
// ---------------------------------------------------------------------------
extern "C" __global__ __launch_bounds__(256, 4)
void k_pair(const float* __restrict__ d3,
            const float* __restrict__ basis,
            const float* __restrict__ W_ii,
            const float* __restrict__ u,
            const unsigned short* __restrict__ vq,
            const unsigned short* __restrict__ qi_bf,
            const int* __restrict__ rowstart,
            const int2* __restrict__ plist2,
            float* __restrict__ out_i1,
            float* __restrict__ out_ix,
            float* __restrict__ p1_agg,
            float* __restrict__ p3_agg)
{
    const int t = threadIdx.x;
    const int w = t >> 6;
    const int l = t & 63;
    const int n = blockIdx.x * 4 + w;        // grid 6250*4 = 25000 exactly

    // W_ii columns l (lo) and 64+l (hi) packed as bf16 pairs: 32 VGPRs
    unsigned int wAB[32];
    #pragma unroll
    for (int c = 0; c < 32; ++c)
        wAB[c] = pack2bf(W_ii[c * 128 + l], W_ii[c * 128 + 64 + l]);

    float uu[4];
    #pragma unroll
    for (int q = 0; q < 4; ++q) uu[q] = u[(size_t)n * 256 + 64 * q + l];
    float qiv[3];
    {
        uint2 iu = *(const uint2*)&qi_bf[(size_t)n * 256 + 4 * l];
        qiv[0] = lo_bf(iu.x); qiv[1] = hi_bf(iu.x); qiv[2] = lo_bf(iu.y);
    }

    const int start = rowstart[n];
    const int end   = rowstart[n + 1];

    float agg1a = 0.0f, agg1b = 0.0f;
    float agg30 = 0.0f, agg31 = 0.0f, agg32 = 0.0f;

    if (start < end) {
        const int last = end - 1;

        int2 pjA = plist2[start];
        uint4 vqA = *(const uint4*)&vq[(size_t)pjA.y * 512 + 8 * l];
        float bsA = basis[(size_t)pjA.x * 8 + (l & 7)];
        float dA0 = d3[3 * (size_t)pjA.x + 0];
        float dA1 = d3[3 * (size_t)pjA.x + 1];
        float dA2 = d3[3 * (size_t)pjA.x + 2];

        int iB = (start + 1 <= last) ? start + 1 : last;
        int2 pjB = plist2[iB];
        uint4 vqB = *(const uint4*)&vq[(size_t)pjB.y * 512 + 8 * l];
        float bsB = basis[(size_t)pjB.x * 8 + (l & 7)];
        float dB0 = d3[3 * (size_t)pjB.x + 0];
        float dB1 = d3[3 * (size_t)pjB.x + 1];
        float dB2 = d3[3 * (size_t)pjB.x + 2];

        int iC = (start + 2 <= last) ? start + 2 : last;
        int2 pjC = plist2[iC];

        for (int it = start; it < end; ++it) {
            // issue stage-C data loads, stage-D index load
            uint4 vqC = *(const uint4*)&vq[(size_t)pjC.y * 512 + 8 * l];
            float bsC = basis[(size_t)pjC.x * 8 + (l & 7)];
            float dC0 = d3[3 * (size_t)pjC.x + 0];
            float dC1 = d3[3 * (size_t)pjC.x + 1];
            float dC2 = d3[3 * (size_t)pjC.x + 2];
            int iD = (it + 3 <= last) ? it + 3 : last;
            int2 pjD = plist2[iD];

            // ---- compute with stage A ----
            float hq0 = tanh_fast(uu[0] + lo_bf(vqA.x));
            float hq1 = tanh_fast(uu[1] + hi_bf(vqA.x));
            float hq2 = tanh_fast(uu[2] + lo_bf(vqA.y));
            float hq3 = tanh_fast(uu[3] + hi_bf(vqA.y));

            float pre[4];
            pre[0] = dpp8_reduce(hq0 * bsA);
            pre[1] = dpp8_reduce(hq1 * bsA);
            pre[2] = dpp8_reduce(hq2 * bsA);
            pre[3] = dpp8_reduce(hq3 * bsA);

            float a00 = 0, a01 = 0, a10 = 0, a11 = 0;
            #pragma unroll
            for (int c = 0; c < 32; c += 2) {
                float p0 = readlane_f(pre[c >> 3], 8 * (c & 7));
                float p1 = readlane_f(pre[(c + 1) >> 3], 8 * ((c + 1) & 7));
                a00 = fmaf(p0, lo_bf_f(wAB[c]), a00);
                a10 = fmaf(p0, hi_bf_f(wAB[c]), a10);
                a01 = fmaf(p1, lo_bf_f(wAB[c + 1]), a01);
                a11 = fmaf(p1, hi_bf_f(wAB[c + 1]), a11);
            }
            const float i10 = tanh_fast(a00 + a01);
            const float i11 = tanh_fast(a10 + a11);

            const size_t pA = (size_t)pjA.x;
            __builtin_nontemporal_store(i10, &out_i1[pA * 128 + l]);
            __builtin_nontemporal_store(i11, &out_i1[pA * 128 + 64 + l]);
            agg1a += i10;
            agg1b += i11;

            float ix0 = (qiv[0] + lo_bf(vqA.z) + dA0) * i11;
            float ix1 = (qiv[1] + hi_bf(vqA.z) + dA1) * i11;
            float ix2 = (qiv[2] + lo_bf(vqA.w) + dA2) * i11;
            __builtin_nontemporal_store(ix0, &out_ix[(pA * 3 + 0) * 64 + l]);
            __builtin_nontemporal_store(ix1, &out_ix[(pA * 3 + 1) * 64 + l]);
            __builtin_nontemporal_store(ix2, &out_ix[(pA * 3 + 2) * 64 + l]);
            agg30 += ix0; agg31 += ix1; agg32 += ix2;

            // rotate stages
            pjA = pjB; vqA = vqB; bsA = bsB; dA0 = dB0; dA1 = dB1; dA2 = dB2;
            pjB = pjC; vqB = vqC; bsB = bsC; dB0 = dC0; dB1 = dC1; dB2 = dC2;
            pjC = pjD;
        }
    }

    p1_agg[(size_t)n * 128 + l]      = agg1a;
    p1_agg[(size_t)n * 128 + 64 + l] = agg1b;
    p3_agg[(size_t)n * 192 + l]       = agg30;
    p3_agg[(size_t)n * 192 + 64 + l]  = agg31;
    p3_agg[(size_t)n * 192 + 128 + l] = agg32;
}

// ---------------------------------------------------------------------------
// K3: per-atom tail.
// ---------------------------------------------------------------------------
extern "C" __global__ __launch_bounds__(256, 4)
void k3_atoms(const float* __restrict__ p1_agg,
              const float* __restrict__ p3_agg,
              const float* __restrict__ W_pp,
              const float* __restrict__ W_ppx,
              const float* __restrict__ wi_dot,
              const float* __restrict__ wj_dot,
              const float* __restrict__ W_pp1,
              const float* __restrict__ b_pp1,
              float* __restrict__ out_p1,
              float* __restrict__ out_p3,
              float* __restrict__ out_dot)
{
    __shared__ float s1[4][128];
    __shared__ float s3[4][192];
    __shared__ float sPm[4][192];
    __shared__ float sCat[4][128];

    const int w = threadIdx.x >> 6;
    const int l = threadIdx.x & 63;
    const int n = blockIdx.x * 4 + w;    // grid = 6250 exactly

    s1[w][l]      = p1_agg[(size_t)n * 128 + l];
    s1[w][64 + l] = p1_agg[(size_t)n * 128 + 64 + l];
    #pragma unroll
    for (int x = 0; x < 3; ++x)
        s3[w][x * 64 + l] = p3_agg[(size_t)n * 192 + x * 64 + l];
    __syncthreads();

    float pn = 0.0f;
    #pragma unroll 4
    for (int k = 0; k < 128; ++k)
        pn = fmaf(s1[w][k], W_pp[k * 64 + l], pn);
    pn = tanh_fast(pn);

    float pm[3];
    #pragma unroll
    for (int x = 0; x < 3; ++x) {
        float s = 0.0f;
        #pragma unroll 4
        for (int c = 0; c < 64; ++c)
            s = fmaf(s3[w][x * 64 + c], W_ppx[c * 64 + l], s);
        pm[x] = s;
        sPm[w][x * 64 + l] = s;
    }
    __syncthreads();

    float dot = 0.0f;
    #pragma unroll
    for (int x = 0; x < 3; ++x) {
        float vi = 0.0f, vj = 0.0f;
        #pragma unroll 4
        for (int c = 0; c < 64; ++c) {
            float a = sPm[w][x * 64 + c];
            vi = fmaf(a, wi_dot[c * 64 + l], vi);
            vj = fmaf(a, wj_dot[c * 64 + l], vj);
        }
        dot = fmaf(vi, vj, dot);
    }

    sCat[w][l]      = pn;
    sCat[w][64 + l] = dot;
    __syncthreads();

    float u1 = b_pp1[l];
    float u2 = b_pp1[64 + l];
    #pragma unroll 4
    for (int k = 0; k < 128; ++k) {
        float ck = sCat[w][k];
        u1 = fmaf(ck, W_pp1[k * 128 + l], u1);
        u2 = fmaf(ck, W_pp1[k * 128 + 64 + l], u2);
    }
    float p1o = tanh_fast(u1);
    float s3v = tanh_fast(u2);

    out_p1[(size_t)n * 64 + l]  = p1o;
    out_dot[(size_t)n * 64 + l] = dot;
    #pragma unroll
    for (int x = 0; x < 3; ++x)
        out_p3[((size_t)n * 3 + x) * 64 + l] = pm[x] * s3v;
}

// ---------------------------------------------------------------------------
extern "C" void kernel_launch(void* const* d_in, const int* in_sizes, int n_in,
                              void* d_out, int out_size, void* d_ws, size_t ws_size,
                              hipStream_t stream)
{
    const int*   ind2   = (const int*)d_in[0];
    const float* p1     = (const float*)d_in[1];
    const float* p3     = (const float*)d_in[2];
    const float* d3     = (const float*)d_in[3];
    const float* basis  = (const float*)d_in[4];
    const float* W_pi   = (const float*)d_in[5];
    const float* b_pi   = (const float*)d_in[6];
    const float* W_ii   = (const float*)d_in[7];
    const float* W_pp   = (const float*)d_in[8];
    const float* wi_pix = (const float*)d_in[9];
    const float* wj_pix = (const float*)d_in[10];
    const float* W_ppx  = (const float*)d_in[11];
    const float* wi_dot = (const float*)d_in[12];
    const float* wj_dot = (const float*)d_in[13];
    const float* W_pp1  = (const float*)d_in[14];
    const float* b_pp1  = (const float*)d_in[15];

    float* out     = (float*)d_out;
    float* out_p1  = out;                      // 25000*64
    float* out_p3  = out + 1600000;            // 25000*192
    float* out_dot = out + 6400000;            // 25000*64
    float* out_i1  = out + 8000000;            // 500000*128
    float* out_ix  = out + 72000000;           // 500000*192

    // workspace (~95MB of the ~2.7GB ws)
    float*          u      = (float*)d_ws;                       // 6,400,000 f32
    unsigned short* vq     = (unsigned short*)(u + 6400000);     // 12,800,000 us (v|qj interleaved)
    unsigned short* qi_bf  = vq + 12800000;                      // 6,400,000 us
    float*          p1_agg = (float*)(qi_bf + 6400000);          // 3,200,000 f32
    float*          p3_agg = p1_agg + 3200000;                   // 4,800,000 f32
    int2*           plist2 = (int2*)(p3_agg + 4800000);          // 500,000 int2 (8B-aligned)
    int*            cnt      = (int*)(plist2 + 500000);          // 25,000
    int*            rowstart = cnt + 25000;                      // 25,001
    int*            cursor   = rowstart + 25001;                 // 25,000

    hipMemsetAsync(cnt, 0, (size_t)75001 * sizeof(int), stream);

    dim3 blk(256);
    k0_uv    <<<dim3(1563), blk, 0, stream>>>(p1, W_pi, b_pi, u, vq);
    k0_q     <<<dim3(6250), blk, 0, stream>>>(p3, wi_pix, wj_pix, qi_bf, vq);
    k_count  <<<dim3(1954), blk, 0, stream>>>(ind2, cnt);
    csr_scan <<<dim3(1), dim3(1024), 0, stream>>>(cnt, rowstart);
    k_scatter<<<dim3(1954), blk, 0, stream>>>(ind2, rowstart, cursor, plist2);
    k_pair   <<<dim3(6250), blk, 0, stream>>>(d3, basis, W_ii, u, vq,
                                              qi_bf, rowstart, plist2,
                                              out_i1, out_ix, p1_agg, p3_agg);
    k3_atoms <<<dim3(6250), blk, 0, stream>>>(p1_agg, p3_agg, W_pp, W_ppx,
                                              wi_dot, wj_dot, W_pp1, b_pp1,
                                              out_p1, out_p3, out_dot);
}

// Round 9
// 590.269 us; speedup vs baseline: 4.0646x; 1.0213x over previous
//
#include <hip/hip_runtime.h>

#define NP 500000
#define NA 25000

__device__ __forceinline__ float tanh_fast(float x) {
    float e = __expf(2.0f * x);
    return 1.0f - 2.0f / (e + 1.0f);
}

// readlane with float bitcast (__builtin_amdgcn_readlane is (int,int);
// passing float value-converts = truncates — the R2/R3 bug).
__device__ __forceinline__ float readlane_f(float v, int lane) {
    int iv = __builtin_bit_cast(int, v);
    int r = __builtin_amdgcn_readlane(iv, lane);
    return __builtin_bit_cast(float, r);
}

// Sum over each consecutive 8-lane group, all in VALU (DPP), no LDS.
__device__ __forceinline__ float dpp8_reduce(float s) {
    int x;
    x = __builtin_amdgcn_update_dpp(0, __builtin_bit_cast(int, s), 0xB1, 0xF, 0xF, true);
    s += __builtin_bit_cast(float, x);
    x = __builtin_amdgcn_update_dpp(0, __builtin_bit_cast(int, s), 0x4E, 0xF, 0xF, true);
    s += __builtin_bit_cast(float, x);
    x = __builtin_amdgcn_update_dpp(0, __builtin_bit_cast(int, s), 0x141, 0xF, 0xF, true);
    s += __builtin_bit_cast(float, x);
    return s;
}

__device__ __forceinline__ unsigned short f2bf(float x) {
    union { float f; unsigned int u; } c; c.f = x;
    unsigned int r = c.u + 0x7FFFu + ((c.u >> 16) & 1u);
    return (unsigned short)(r >> 16);
}
__device__ __forceinline__ float bf2f(unsigned short h) {
    union { unsigned int u; float f; } c; c.u = ((unsigned int)h) << 16;
    return c.f;
}
__device__ __forceinline__ unsigned int pack2bf(float a, float b) {
    return (unsigned int)f2bf(a) | ((unsigned int)f2bf(b) << 16);
}
__device__ __forceinline__ float lo_bf(unsigned int x) { return bf2f((unsigned short)(x & 0xffffu)); }
__device__ __forceinline__ float hi_bf(unsigned int x) { return bf2f((unsigned short)(x >> 16)); }
__device__ __forceinline__ float lo_bf_f(unsigned int x) {
    return __builtin_bit_cast(float, x << 16);
}
__device__ __forceinline__ float hi_bf_f(unsigned int x) {
    return __builtin_bit_cast(float, x & 0xffff0000u);
}

// ---------------------------------------------------------------------------
// K0a: 16 atoms/block.  u = p1 @ W_pi[0:64,:] + b_pi  (f32 [atom][col])
//      v = p1 @ W_pi[64:128,:] -> vq[atom][l*8 + 0..3]  (bf16, col = 64q+l)
// ---------------------------------------------------------------------------
extern "C" __global__ __launch_bounds__(256, 2)
void k0_uv(const float* __restrict__ p1,
           const float* __restrict__ W_pi,
           const float* __restrict__ b_pi,
           float* __restrict__ u,
           unsigned short* __restrict__ vq)
{
    __shared__ float sW[32 * 256];     // 32 KB
    __shared__ float sp1[16 * 64];     //  4 KB

    const int t = threadIdx.x;
    const int wv = t >> 6;
    const int l = t & 63;
    const int atom0 = blockIdx.x * 16;

    #pragma unroll
    for (int f = 0; f < 4; ++f) {
        int idx = f * 256 + t;
        int at = atom0 + (idx >> 6);
        int atc = at < NA ? at : NA - 1;
        sp1[idx] = p1[(size_t)atc * 64 + (idx & 63)];
    }

    float accu[4][4] = {{0}}, accv[4][4] = {{0}};

    #pragma unroll
    for (int s = 0; s < 4; ++s) {
        __syncthreads();
        {
            const float4* src = (const float4*)(W_pi + s * 32 * 256);
            float4* dst = (float4*)sW;
            #pragma unroll
            for (int f = 0; f < 8; ++f) dst[f * 256 + t] = src[f * 256 + t];
        }
        __syncthreads();
        const int kbase = (s & 1) * 32;
        #pragma unroll 2
        for (int k = 0; k < 32; ++k) {
            float wq[4];
            #pragma unroll
            for (int q = 0; q < 4; ++q) wq[q] = sW[k * 256 + 64 * q + l];
            #pragma unroll
            for (int a = 0; a < 4; ++a) {
                float pv = sp1[(wv * 4 + a) * 64 + kbase + k];
                #pragma unroll
                for (int q = 0; q < 4; ++q) {
                    if (s < 2) accu[a][q] = fmaf(pv, wq[q], accu[a][q]);
                    else       accv[a][q] = fmaf(pv, wq[q], accv[a][q]);
                }
            }
        }
    }

    #pragma unroll
    for (int a = 0; a < 4; ++a) {
        const int at = atom0 + wv * 4 + a;
        if (at < NA) {
            #pragma unroll
            for (int q = 0; q < 4; ++q)
                u[(size_t)at * 256 + 64 * q + l] = accu[a][q] + b_pi[64 * q + l];
            uint2 vv;
            vv.x = pack2bf(accv[a][0], accv[a][1]);
            vv.y = pack2bf(accv[a][2], accv[a][3]);
            *(uint2*)&vq[(size_t)at * 512 + 8 * l] = vv;
        }
    }
}

// ---------------------------------------------------------------------------
// K0b (+fused pair count): qi = p3 @ wi_pix -> qi_bf[atom][4l+x];
//                          qj = p3 @ wj_pix -> vq[atom][8l+4..6]
// ---------------------------------------------------------------------------
extern "C" __global__ __launch_bounds__(256, 4)
void k0_q(const float* __restrict__ p3,
          const float* __restrict__ wi_pix,
          const float* __restrict__ wj_pix,
          const int* __restrict__ ind2,
          int* __restrict__ cnt,
          unsigned short* __restrict__ qi_bf,
          unsigned short* __restrict__ vq)
{
    __shared__ float sWi[64 * 64];
    __shared__ float sWj[64 * 64];

    const int t = threadIdx.x;

    // fused k_count: first 1954 blocks also count pairs
    {
        int gp = blockIdx.x * 256 + t;
        if (gp < NP) atomicAdd(&cnt[ind2[2 * gp]], 1);
    }

    {
        const float4* si = (const float4*)wi_pix;
        const float4* sj = (const float4*)wj_pix;
        float4* di = (float4*)sWi;
        float4* dj = (float4*)sWj;
        #pragma unroll
        for (int f = 0; f < 4; ++f) { di[f * 256 + t] = si[f * 256 + t]; dj[f * 256 + t] = sj[f * 256 + t]; }
    }
    __syncthreads();

    const int w = t >> 6;
    const int l = t & 63;
    const int atom = blockIdx.x * 4 + w;     // grid 6250 -> < 25000

    float val0 = p3[((size_t)atom * 3 + 0) * 64 + l];
    float val1 = p3[((size_t)atom * 3 + 1) * 64 + l];
    float val2 = p3[((size_t)atom * 3 + 2) * 64 + l];

    float ai[3] = {0, 0, 0}, aj[3] = {0, 0, 0};
    #pragma unroll 8
    for (int k = 0; k < 64; ++k) {
        float a0 = readlane_f(val0, k);
        float a1 = readlane_f(val1, k);
        float a2 = readlane_f(val2, k);
        float wi = sWi[k * 64 + l];
        float wj = sWj[k * 64 + l];
        ai[0] = fmaf(a0, wi, ai[0]); aj[0] = fmaf(a0, wj, aj[0]);
        ai[1] = fmaf(a1, wi, ai[1]); aj[1] = fmaf(a1, wj, aj[1]);
        ai[2] = fmaf(a2, wi, ai[2]); aj[2] = fmaf(a2, wj, aj[2]);
    }
    uint2 iu, ju;
    iu.x = pack2bf(ai[0], ai[1]); iu.y = pack2bf(ai[2], 0.0f);
    ju.x = pack2bf(aj[0], aj[1]); ju.y = pack2bf(aj[2], 0.0f);
    *(uint2*)&qi_bf[(size_t)atom * 256 + 4 * l] = iu;
    *(uint2*)&vq[(size_t)atom * 512 + 8 * l + 4] = ju;
}

// ---------------------------------------------------------------------------
// CSR build
// ---------------------------------------------------------------------------
extern "C" __global__ __launch_bounds__(1024)
void csr_scan(const int* __restrict__ cnt, int* __restrict__ rowstart)
{
    __shared__ int ssum[1024];
    const int t = threadIdx.x;
    const int base = t * 25;

    int s = 0;
    #pragma unroll 5
    for (int i = 0; i < 25; ++i) {
        int idx = base + i;
        s += (idx < NA) ? cnt[idx] : 0;
    }
    ssum[t] = s;
    __syncthreads();
    for (int off = 1; off < 1024; off <<= 1) {
        int vv = (t >= off) ? ssum[t - off] : 0;
        __syncthreads();
        ssum[t] += vv;
        __syncthreads();
    }
    int run = (t > 0) ? ssum[t - 1] : 0;
    for (int i = 0; i < 25; ++i) {
        int idx = base + i;
        if (idx <= NA) rowstart[idx] = run;
        run += (idx < NA) ? cnt[idx] : 0;
    }
}

extern "C" __global__ void k_scatter(const int* __restrict__ ind2,
                                     const int* __restrict__ rowstart,
                                     int* __restrict__ cursor,
                                     int2* __restrict__ plist2)
{
    int p = blockIdx.x * 256 + threadIdx.x;
    if (p < NP) {
        int ii = ind2[2 * p];
        int jj = ind2[2 * p + 1];
        int pos = atomicAdd(&cursor[ii], 1);
        plist2[rowstart[ii] + pos] = make_int2(p, jj);
    }
}

// ---------------------------------------------------------------------------
// K_pair: wave per atom; TWO pairs per iteration (independent chains),
// prefetch 1 iteration (=2 pairs) ahead. One 16B gather per pair.
// ---------------------------------------------------------------------------
extern "C" __global__ __launch_bounds__(256, 4)
void k_pair(const float* __restrict__ d3,
            const float* __restrict__ basis,
            const float* __restrict__ W_ii,
            const float* __restrict__ u,
            const unsigned short* __restrict__ vq,
            const unsigned short* __restrict__ qi_bf,
            const int* __restrict__ rowstart,
            const int2* __restrict__ plist2,
            float* __restrict__ out_i1,
            float* __restrict__ out_ix,
            float* __restrict__ p1_agg,
            float* __restrict__ p3_agg)
{
    const int t = threadIdx.x;
    const int w = t >> 6;
    const int l = t & 63;
    const int n = blockIdx.x * 4 + w;        // grid 6250*4 = 25000 exactly

    // W_ii columns l (lo) and 64+l (hi) packed as bf16 pairs: 32 VGPRs
    unsigned int wAB[32];
    #pragma unroll
    for (int c = 0; c < 32; ++c)
        wAB[c] = pack2bf(W_ii[c * 128 + l], W_ii[c * 128 + 64 + l]);

    float uu[4];
    #pragma unroll
    for (int q = 0; q < 4; ++q) uu[q] = u[(size_t)n * 256 + 64 * q + l];
    float qiv[3];
    {
        uint2 iu = *(const uint2*)&qi_bf[(size_t)n * 256 + 4 * l];
        qiv[0] = lo_bf(iu.x); qiv[1] = hi_bf(iu.x); qiv[2] = lo_bf(iu.y);
    }

    const int start = rowstart[n];
    const int end   = rowstart[n + 1];

    float agg1a = 0.0f, agg1b = 0.0f;
    float agg30 = 0.0f, agg31 = 0.0f, agg32 = 0.0f;

    if (start < end) {
        const int last = end - 1;

        // slot S0/S1 = current two pairs; T0/T1 = next two (in flight)
        int2 pj0, pj1;
        uint4 vq0, vq1;
        float bs0, bs1;
        float d0x, d0y, d0z, d1x, d1y, d1z;

        {
            int iA = start;
            int iB = (start + 1 <= last) ? start + 1 : last;
            pj0 = plist2[iA];
            pj1 = plist2[iB];
            vq0 = *(const uint4*)&vq[(size_t)pj0.y * 512 + 8 * l];
            vq1 = *(const uint4*)&vq[(size_t)pj1.y * 512 + 8 * l];
            bs0 = basis[(size_t)pj0.x * 8 + (l & 7)];
            bs1 = basis[(size_t)pj1.x * 8 + (l & 7)];
            d0x = d3[3 * (size_t)pj0.x + 0]; d0y = d3[3 * (size_t)pj0.x + 1]; d0z = d3[3 * (size_t)pj0.x + 2];
            d1x = d3[3 * (size_t)pj1.x + 0]; d1y = d3[3 * (size_t)pj1.x + 1]; d1z = d3[3 * (size_t)pj1.x + 2];
        }

        for (int it = start; it < end; it += 2) {
            // ---- prefetch next two pairs ----
            int iC = (it + 2 <= last) ? it + 2 : last;
            int iD = (it + 3 <= last) ? it + 3 : last;
            int2 pjT0 = plist2[iC];
            int2 pjT1 = plist2[iD];
            uint4 vqT0 = *(const uint4*)&vq[(size_t)pjT0.y * 512 + 8 * l];
            uint4 vqT1 = *(const uint4*)&vq[(size_t)pjT1.y * 512 + 8 * l];
            float bsT0 = basis[(size_t)pjT0.x * 8 + (l & 7)];
            float bsT1 = basis[(size_t)pjT1.x * 8 + (l & 7)];
            float dT0x = d3[3 * (size_t)pjT0.x + 0];
            float dT0y = d3[3 * (size_t)pjT0.x + 1];
            float dT0z = d3[3 * (size_t)pjT0.x + 2];
            float dT1x = d3[3 * (size_t)pjT1.x + 0];
            float dT1y = d3[3 * (size_t)pjT1.x + 1];
            float dT1z = d3[3 * (size_t)pjT1.x + 2];

            // ---- compute pair 0 and pair 1 with interleaved chains ----
            float h00 = tanh_fast(uu[0] + lo_bf(vq0.x));
            float h10 = tanh_fast(uu[0] + lo_bf(vq1.x));
            float h01 = tanh_fast(uu[1] + hi_bf(vq0.x));
            float h11 = tanh_fast(uu[1] + hi_bf(vq1.x));
            float h02 = tanh_fast(uu[2] + lo_bf(vq0.y));
            float h12 = tanh_fast(uu[2] + lo_bf(vq1.y));
            float h03 = tanh_fast(uu[3] + hi_bf(vq0.y));
            float h13 = tanh_fast(uu[3] + hi_bf(vq1.y));

            float pre0[4], pre1[4];
            pre0[0] = dpp8_reduce(h00 * bs0);
            pre1[0] = dpp8_reduce(h10 * bs1);
            pre0[1] = dpp8_reduce(h01 * bs0);
            pre1[1] = dpp8_reduce(h11 * bs1);
            pre0[2] = dpp8_reduce(h02 * bs0);
            pre1[2] = dpp8_reduce(h12 * bs1);
            pre0[3] = dpp8_reduce(h03 * bs0);
            pre1[3] = dpp8_reduce(h13 * bs1);

            float a0A = 0, a0B = 0, a1A = 0, a1B = 0;
            float b0A = 0, b0B = 0, b1A = 0, b1B = 0;
            #pragma unroll
            for (int c = 0; c < 32; c += 2) {
                float p00 = readlane_f(pre0[c >> 3], 8 * (c & 7));
                float p10 = readlane_f(pre1[c >> 3], 8 * (c & 7));
                float p01 = readlane_f(pre0[(c + 1) >> 3], 8 * ((c + 1) & 7));
                float p11 = readlane_f(pre1[(c + 1) >> 3], 8 * ((c + 1) & 7));
                float wlo0 = lo_bf_f(wAB[c]), whi0 = hi_bf_f(wAB[c]);
                float wlo1 = lo_bf_f(wAB[c + 1]), whi1 = hi_bf_f(wAB[c + 1]);
                a0A = fmaf(p00, wlo0, a0A);  b0A = fmaf(p00, whi0, b0A);
                a1A = fmaf(p10, wlo0, a1A);  b1A = fmaf(p10, whi0, b1A);
                a0B = fmaf(p01, wlo1, a0B);  b0B = fmaf(p01, whi1, b0B);
                a1B = fmaf(p11, wlo1, a1B);  b1B = fmaf(p11, whi1, b1B);
            }
            const float i10_0 = tanh_fast(a0A + a0B);
            const float i11_0 = tanh_fast(b0A + b0B);
            const float i10_1 = tanh_fast(a1A + a1B);
            const float i11_1 = tanh_fast(b1A + b1B);

            // ---- emit pair 0 (always valid) ----
            {
                const size_t pA = (size_t)pj0.x;
                __builtin_nontemporal_store(i10_0, &out_i1[pA * 128 + l]);
                __builtin_nontemporal_store(i11_0, &out_i1[pA * 128 + 64 + l]);
                agg1a += i10_0;
                agg1b += i11_0;
                float ix0 = (qiv[0] + lo_bf(vq0.z) + d0x) * i11_0;
                float ix1 = (qiv[1] + hi_bf(vq0.z) + d0y) * i11_0;
                float ix2 = (qiv[2] + lo_bf(vq0.w) + d0z) * i11_0;
                __builtin_nontemporal_store(ix0, &out_ix[(pA * 3 + 0) * 64 + l]);
                __builtin_nontemporal_store(ix1, &out_ix[(pA * 3 + 1) * 64 + l]);
                __builtin_nontemporal_store(ix2, &out_ix[(pA * 3 + 2) * 64 + l]);
                agg30 += ix0; agg31 += ix1; agg32 += ix2;
            }
            // ---- emit pair 1 (wave-uniform validity) ----
            if (it + 1 < end) {
                const size_t pA = (size_t)pj1.x;
                __builtin_nontemporal_store(i10_1, &out_i1[pA * 128 + l]);
                __builtin_nontemporal_store(i11_1, &out_i1[pA * 128 + 64 + l]);
                agg1a += i10_1;
                agg1b += i11_1;
                float ix0 = (qiv[0] + lo_bf(vq1.z) + d1x) * i11_1;
                float ix1 = (qiv[1] + hi_bf(vq1.z) + d1y) * i11_1;
                float ix2 = (qiv[2] + lo_bf(vq1.w) + d1z) * i11_1;
                __builtin_nontemporal_store(ix0, &out_ix[(pA * 3 + 0) * 64 + l]);
                __builtin_nontemporal_store(ix1, &out_ix[(pA * 3 + 1) * 64 + l]);
                __builtin_nontemporal_store(ix2, &out_ix[(pA * 3 + 2) * 64 + l]);
                agg30 += ix0; agg31 += ix1; agg32 += ix2;
            }

            // rotate
            pj0 = pjT0; vq0 = vqT0; bs0 = bsT0; d0x = dT0x; d0y = dT0y; d0z = dT0z;
            pj1 = pjT1; vq1 = vqT1; bs1 = bsT1; d1x = dT1x; d1y = dT1y; d1z = dT1z;
        }
    }

    p1_agg[(size_t)n * 128 + l]      = agg1a;
    p1_agg[(size_t)n * 128 + 64 + l] = agg1b;
    p3_agg[(size_t)n * 192 + l]       = agg30;
    p3_agg[(size_t)n * 192 + 64 + l]  = agg31;
    p3_agg[(size_t)n * 192 + 128 + l] = agg32;
}

// ---------------------------------------------------------------------------
// K3: per-atom tail.
// ---------------------------------------------------------------------------
extern "C" __global__ __launch_bounds__(256, 4)
void k3_atoms(const float* __restrict__ p1_agg,
              const float* __restrict__ p3_agg,
              const float* __restrict__ W_pp,
              const float* __restrict__ W_ppx,
              const float* __restrict__ wi_dot,
              const float* __restrict__ wj_dot,
              const float* __restrict__ W_pp1,
              const float* __restrict__ b_pp1,
              float* __restrict__ out_p1,
              float* __restrict__ out_p3,
              float* __restrict__ out_dot)
{
    __shared__ float s1[4][128];
    __shared__ float s3[4][192];
    __shared__ float sPm[4][192];
    __shared__ float sCat[4][128];

    const int w = threadIdx.x >> 6;
    const int l = threadIdx.x & 63;
    const int n = blockIdx.x * 4 + w;    // grid = 6250 exactly

    s1[w][l]      = p1_agg[(size_t)n * 128 + l];
    s1[w][64 + l] = p1_agg[(size_t)n * 128 + 64 + l];
    #pragma unroll
    for (int x = 0; x < 3; ++x)
        s3[w][x * 64 + l] = p3_agg[(size_t)n * 192 + x * 64 + l];
    __syncthreads();

    float pn = 0.0f;
    #pragma unroll 4
    for (int k = 0; k < 128; ++k)
        pn = fmaf(s1[w][k], W_pp[k * 64 + l], pn);
    pn = tanh_fast(pn);

    float pm[3];
    #pragma unroll
    for (int x = 0; x < 3; ++x) {
        float s = 0.0f;
        #pragma unroll 4
        for (int c = 0; c < 64; ++c)
            s = fmaf(s3[w][x * 64 + c], W_ppx[c * 64 + l], s);
        pm[x] = s;
        sPm[w][x * 64 + l] = s;
    }
    __syncthreads();

    float dot = 0.0f;
    #pragma unroll
    for (int x = 0; x < 3; ++x) {
        float vi = 0.0f, vj = 0.0f;
        #pragma unroll 4
        for (int c = 0; c < 64; ++c) {
            float a = sPm[w][x * 64 + c];
            vi = fmaf(a, wi_dot[c * 64 + l], vi);
            vj = fmaf(a, wj_dot[c * 64 + l], vj);
        }
        dot = fmaf(vi, vj, dot);
    }

    sCat[w][l]      = pn;
    sCat[w][64 + l] = dot;
    __syncthreads();

    float u1 = b_pp1[l];
    float u2 = b_pp1[64 + l];
    #pragma unroll 4
    for (int k = 0; k < 128; ++k) {
        float ck = sCat[w][k];
        u1 = fmaf(ck, W_pp1[k * 128 + l], u1);
        u2 = fmaf(ck, W_pp1[k * 128 + 64 + l], u2);
    }
    float p1o = tanh_fast(u1);
    float s3v = tanh_fast(u2);

    out_p1[(size_t)n * 64 + l]  = p1o;
    out_dot[(size_t)n * 64 + l] = dot;
    #pragma unroll
    for (int x = 0; x < 3; ++x)
        out_p3[((size_t)n * 3 + x) * 64 + l] = pm[x] * s3v;
}

// ---------------------------------------------------------------------------
extern "C" void kernel_launch(void* const* d_in, const int* in_sizes, int n_in,
                              void* d_out, int out_size, void* d_ws, size_t ws_size,
                              hipStream_t stream)
{
    const int*   ind2   = (const int*)d_in[0];
    const float* p1     = (const float*)d_in[1];
    const float* p3     = (const float*)d_in[2];
    const float* d3     = (const float*)d_in[3];
    const float* basis  = (const float*)d_in[4];
    const float* W_pi   = (const float*)d_in[5];
    const float* b_pi   = (const float*)d_in[6];
    const float* W_ii   = (const float*)d_in[7];
    const float* W_pp   = (const float*)d_in[8];
    const float* wi_pix = (const float*)d_in[9];
    const float* wj_pix = (const float*)d_in[10];
    const float* W_ppx  = (const float*)d_in[11];
    const float* wi_dot = (const float*)d_in[12];
    const float* wj_dot = (const float*)d_in[13];
    const float* W_pp1  = (const float*)d_in[14];
    const float* b_pp1  = (const float*)d_in[15];

    float* out     = (float*)d_out;
    float* out_p1  = out;                      // 25000*64
    float* out_p3  = out + 1600000;            // 25000*192
    float* out_dot = out + 6400000;            // 25000*64
    float* out_i1  = out + 8000000;            // 500000*128
    float* out_ix  = out + 72000000;           // 500000*192

    // workspace (~95MB of the ~2.7GB ws)
    float*          u      = (float*)d_ws;                       // 6,400,000 f32
    unsigned short* vq     = (unsigned short*)(u + 6400000);     // 12,800,000 us (v|qj interleaved)
    unsigned short* qi_bf  = vq + 12800000;                      // 6,400,000 us
    float*          p1_agg = (float*)(qi_bf + 6400000);          // 3,200,000 f32
    float*          p3_agg = p1_agg + 3200000;                   // 4,800,000 f32
    int2*           plist2 = (int2*)(p3_agg + 4800000);          // 500,000 int2 (8B-aligned)
    int*            cnt      = (int*)(plist2 + 500000);          // 25,000
    int*            rowstart = cnt + 25000;                      // 25,001
    int*            cursor   = rowstart + 25001;                 // 25,000

    hipMemsetAsync(cnt, 0, (size_t)75001 * sizeof(int), stream);

    dim3 blk(256);
    k0_uv    <<<dim3(1563), blk, 0, stream>>>(p1, W_pi, b_pi, u, vq);
    k0_q     <<<dim3(6250), blk, 0, stream>>>(p3, wi_pix, wj_pix, ind2, cnt,
                                              qi_bf, vq);
    csr_scan <<<dim3(1), dim3(1024), 0, stream>>>(cnt, rowstart);
    k_scatter<<<dim3(1954), blk, 0, stream>>>(ind2, rowstart, cursor, plist2);
    k_pair   <<<dim3(6250), blk, 0, stream>>>(d3, basis, W_ii, u, vq,
                                              qi_bf, rowstart, plist2,
                                              out_i1, out_ix, p1_agg, p3_agg);
    k3_atoms <<<dim3(6250), blk, 0, stream>>>(p1_agg, p3_agg, W_pp, W_ppx,
                                              wi_dot, wj_dot, W_pp1, b_pp1,
                                              out_p1, out_p3, out_dot);
}